// Round 1
// baseline (810.238 us; speedup 1.0000x reference)
//
#include <hip/hip_runtime.h>
#include <hip/hip_bf16.h>
#include <cstddef>

// Problem constants: B=1, L=256, D=128, H=4, hd=32
#define DD 128

typedef unsigned short u16;

__device__ __forceinline__ float bf2f(u16 u) {
    return __uint_as_float(((unsigned int)u) << 16);
}

// ---------------- K1: QKV projection ----------------
// Y[t][e] = sum_d X[t][d] * W[e][d] + bias[e], e in [0,384). Y stored bf16.
// If transposed, token t reads X row ((t&255)*256 + (t>>8)).
__global__ __launch_bounds__(512) void proj_qkv_kernel(
    const float* __restrict__ X, const float* __restrict__ W,
    const float* __restrict__ bias, __hip_bfloat16* __restrict__ Y,
    int transposed)
{
    __shared__ float xs[64][132];
    __shared__ float wl[128][132];
    const int tid = threadIdx.x;
    const int tok0 = blockIdx.x * 64;

    // stage X tile: 64 rows x 128 f32 = 2048 float4
    #pragma unroll
    for (int k = 0; k < 4; ++k) {
        int f = tid + k * 512;
        int row = f >> 5, c4 = f & 31;
        int t = tok0 + row;
        int xrow = transposed ? ((t & 255) * 256 + (t >> 8)) : t;
        float4 v = reinterpret_cast<const float4*>(X + (size_t)xrow * DD)[c4];
        reinterpret_cast<float4*>(&xs[row][0])[c4] = v;
    }

    const int eg = tid & 31;   // e = eg + 32*j
    const int tg = tid >> 5;   // tokens tg + 16*i

    for (int c = 0; c < 3; ++c) {
        __syncthreads();
        // stage W chunk: rows c*128 .. c*128+127
        #pragma unroll
        for (int k = 0; k < 8; ++k) {
            int f = tid + k * 512;
            int row = f >> 5, c4 = f & 31;
            float4 v = reinterpret_cast<const float4*>(W + (size_t)(c * 128 + row) * DD)[c4];
            reinterpret_cast<float4*>(&wl[row][0])[c4] = v;
        }
        __syncthreads();

        float acc[4][4] = {};
        #pragma unroll 4
        for (int d4 = 0; d4 < 32; ++d4) {
            float4 xv[4], wv[4];
            #pragma unroll
            for (int i = 0; i < 4; ++i)
                xv[i] = reinterpret_cast<const float4*>(&xs[tg + i * 16][0])[d4];
            #pragma unroll
            for (int j = 0; j < 4; ++j)
                wv[j] = reinterpret_cast<const float4*>(&wl[eg + j * 32][0])[d4];
            #pragma unroll
            for (int i = 0; i < 4; ++i)
                #pragma unroll
                for (int j = 0; j < 4; ++j)
                    acc[i][j] += xv[i].x * wv[j].x + xv[i].y * wv[j].y
                               + xv[i].z * wv[j].z + xv[i].w * wv[j].w;
        }

        #pragma unroll
        for (int j = 0; j < 4; ++j) {
            int e = c * 128 + eg + j * 32;
            float b = bias[e];
            #pragma unroll
            for (int i = 0; i < 4; ++i) {
                int t = tok0 + tg + i * 16;
                Y[(size_t)t * 384 + e] = __float2bfloat16(acc[i][j] + b);
            }
        }
    }
}

// ---------------- K2: attention over one (row, head, qtile) ----------------
// QKV layout: [256 rows][256 seq][384], q at [0,128), k at [128,256), v at [256,384)
// O layout:   [256 rows][256 seq][128] bf16 (pre-out-projection attention output)
__global__ __launch_bounds__(512) void attn_kernel(
    const __hip_bfloat16* __restrict__ QKV, __hip_bfloat16* __restrict__ O)
{
    __shared__ float ks[256][36];
    __shared__ float vs[256][36];
    const int tid = threadIdx.x;
    const int qt = blockIdx.x, h = blockIdx.y, r = blockIdx.z;
    const u16* Q16 = reinterpret_cast<const u16*>(QKV);
    const size_t rowbase = (size_t)r * 256 * 384;

    // stage K and V (256 x 32 bf16 each)
    #pragma unroll
    for (int k = 0; k < 4; ++k) {
        int f = tid + k * 512;     // quad index 0..2047
        int s = f >> 3, d4 = f & 7;
        const u16* kp = Q16 + rowbase + (size_t)s * 384 + 128 + h * 32 + d4 * 4;
        ushort4 kv = *reinterpret_cast<const ushort4*>(kp);
        ushort4 vv = *reinterpret_cast<const ushort4*>(kp + 128);
        ks[s][d4*4+0] = bf2f(kv.x); ks[s][d4*4+1] = bf2f(kv.y);
        ks[s][d4*4+2] = bf2f(kv.z); ks[s][d4*4+3] = bf2f(kv.w);
        vs[s][d4*4+0] = bf2f(vv.x); vs[s][d4*4+1] = bf2f(vv.y);
        vs[s][d4*4+2] = bf2f(vv.z); vs[s][d4*4+3] = bf2f(vv.w);
    }

    const int qp = tid >> 4;   // 0..31 -> query pair
    const int kg = tid & 15;   // key group: keys kg + 16*kk
    float qreg[2][32];
    #pragma unroll
    for (int qi = 0; qi < 2; ++qi) {
        int lq = qt * 64 + qp * 2 + qi;
        const u16* qptr = Q16 + rowbase + (size_t)lq * 384 + h * 32;
        #pragma unroll
        for (int d4 = 0; d4 < 8; ++d4) {
            ushort4 u = *reinterpret_cast<const ushort4*>(qptr + d4 * 4);
            qreg[qi][d4*4+0] = bf2f(u.x); qreg[qi][d4*4+1] = bf2f(u.y);
            qreg[qi][d4*4+2] = bf2f(u.z); qreg[qi][d4*4+3] = bf2f(u.w);
        }
    }
    __syncthreads();

    // scores for this thread's 2 queries x 16 keys
    float sv[2][16];
    #pragma unroll
    for (int kk = 0; kk < 16; ++kk) {
        int kidx = kg + kk * 16;
        const float4* krow = reinterpret_cast<const float4*>(&ks[kidx][0]);
        float a0 = 0.f, a1 = 0.f;
        #pragma unroll
        for (int d4 = 0; d4 < 8; ++d4) {
            float4 kv = krow[d4];
            a0 += qreg[0][d4*4+0]*kv.x + qreg[0][d4*4+1]*kv.y
                + qreg[0][d4*4+2]*kv.z + qreg[0][d4*4+3]*kv.w;
            a1 += qreg[1][d4*4+0]*kv.x + qreg[1][d4*4+1]*kv.y
                + qreg[1][d4*4+2]*kv.z + qreg[1][d4*4+3]*kv.w;
        }
        sv[0][kk] = a0; sv[1][kk] = a1;
    }

    const float scale = 0.17677669529663687f;  // 1/sqrt(32)
    float m0 = -1e30f, m1 = -1e30f;
    #pragma unroll
    for (int kk = 0; kk < 16; ++kk) { m0 = fmaxf(m0, sv[0][kk]); m1 = fmaxf(m1, sv[1][kk]); }
    #pragma unroll
    for (int st = 1; st < 16; st <<= 1) {
        m0 = fmaxf(m0, __shfl_xor(m0, st, 16));
        m1 = fmaxf(m1, __shfl_xor(m1, st, 16));
    }
    float l0 = 0.f, l1 = 0.f;
    #pragma unroll
    for (int kk = 0; kk < 16; ++kk) {
        float p0 = __expf((sv[0][kk] - m0) * scale);
        float p1 = __expf((sv[1][kk] - m1) * scale);
        sv[0][kk] = p0; sv[1][kk] = p1;
        l0 += p0; l1 += p1;
    }
    #pragma unroll
    for (int st = 1; st < 16; st <<= 1) {
        l0 += __shfl_xor(l0, st, 16);
        l1 += __shfl_xor(l1, st, 16);
    }

    // PV: partial over this thread's 16 keys
    float acc[2][32] = {};
    #pragma unroll
    for (int kk = 0; kk < 16; ++kk) {
        int kidx = kg + kk * 16;
        const float4* vrow = reinterpret_cast<const float4*>(&vs[kidx][0]);
        float p0 = sv[0][kk], p1 = sv[1][kk];
        #pragma unroll
        for (int d4 = 0; d4 < 8; ++d4) {
            float4 vv = vrow[d4];
            acc[0][d4*4+0] += p0*vv.x; acc[0][d4*4+1] += p0*vv.y;
            acc[0][d4*4+2] += p0*vv.z; acc[0][d4*4+3] += p0*vv.w;
            acc[1][d4*4+0] += p1*vv.x; acc[1][d4*4+1] += p1*vv.y;
            acc[1][d4*4+2] += p1*vv.z; acc[1][d4*4+3] += p1*vv.w;
        }
    }
    // butterfly reduce across the 16 key-group lanes
    #pragma unroll
    for (int d = 0; d < 32; ++d) {
        #pragma unroll
        for (int st = 1; st < 16; st <<= 1) {
            acc[0][d] += __shfl_xor(acc[0][d], st, 16);
            acc[1][d] += __shfl_xor(acc[1][d], st, 16);
        }
    }

    float inv0 = 1.f / l0, inv1 = 1.f / l1;
    // each lane writes its 2-wide d-slice (static register indexing via masked select)
    float o00 = 0.f, o01 = 0.f, o10 = 0.f, o11 = 0.f;
    #pragma unroll
    for (int dh = 0; dh < 16; ++dh) {
        if (dh == kg) {
            o00 = acc[0][2*dh]; o01 = acc[0][2*dh+1];
            o10 = acc[1][2*dh]; o11 = acc[1][2*dh+1];
        }
    }
    int lq = qt * 64 + qp * 2;
    __hip_bfloat16* op0 = O + ((size_t)r * 256 + lq) * 128 + h * 32 + kg * 2;
    op0[0] = __float2bfloat16(o00 * inv0);
    op0[1] = __float2bfloat16(o01 * inv0);
    __hip_bfloat16* op1 = op0 + 128;
    op1[0] = __float2bfloat16(o10 * inv1);
    op1[1] = __float2bfloat16(o11 * inv1);
}

// ---------------- K3: out-projection + bias + residual + LayerNorm ----------------
// OUT[t] = LN( RES[t] + A[arow(t)] @ W^T + bias )
__global__ __launch_bounds__(512) void proj_ln_kernel(
    const __hip_bfloat16* __restrict__ A, const float* __restrict__ W,
    const float* __restrict__ bias, const float* __restrict__ RES,
    const float* __restrict__ gamma, const float* __restrict__ beta,
    float* __restrict__ OUT, int transposed)
{
    __shared__ float xs[64][132];
    __shared__ float wl[128][132];
    const int tid = threadIdx.x;
    const int tok0 = blockIdx.x * 64;
    const u16* A16 = reinterpret_cast<const u16*>(A);

    #pragma unroll
    for (int k = 0; k < 4; ++k) {
        int f = tid + k * 512;     // quad 0..2047
        int row = f >> 5, q4 = f & 31;
        int t = tok0 + row;
        int arow = transposed ? ((t & 255) * 256 + (t >> 8)) : t;
        ushort4 u = *reinterpret_cast<const ushort4*>(A16 + (size_t)arow * 128 + q4 * 4);
        xs[row][q4*4+0] = bf2f(u.x); xs[row][q4*4+1] = bf2f(u.y);
        xs[row][q4*4+2] = bf2f(u.z); xs[row][q4*4+3] = bf2f(u.w);
    }
    #pragma unroll
    for (int k = 0; k < 8; ++k) {
        int f = tid + k * 512;
        int row = f >> 5, q4 = f & 31;
        float4 v = reinterpret_cast<const float4*>(W + (size_t)row * DD)[q4];
        reinterpret_cast<float4*>(&wl[row][0])[q4] = v;
    }
    __syncthreads();

    const int eg = tid & 31, tg = tid >> 5;
    float acc[4][4] = {};
    #pragma unroll 4
    for (int d4 = 0; d4 < 32; ++d4) {
        float4 xv[4], wv[4];
        #pragma unroll
        for (int i = 0; i < 4; ++i)
            xv[i] = reinterpret_cast<const float4*>(&xs[tg + i * 16][0])[d4];
        #pragma unroll
        for (int j = 0; j < 4; ++j)
            wv[j] = reinterpret_cast<const float4*>(&wl[eg + j * 32][0])[d4];
        #pragma unroll
        for (int i = 0; i < 4; ++i)
            #pragma unroll
            for (int j = 0; j < 4; ++j)
                acc[i][j] += xv[i].x * wv[j].x + xv[i].y * wv[j].y
                           + xv[i].z * wv[j].z + xv[i].w * wv[j].w;
    }
    __syncthreads();            // all xs reads done
    // write projected y back into xs
    #pragma unroll
    for (int j = 0; j < 4; ++j) {
        float b = bias[eg + j * 32];
        #pragma unroll
        for (int i = 0; i < 4; ++i)
            xs[tg + i * 16][eg + j * 32] = acc[i][j] + b;
    }
    __syncthreads();

    // LayerNorm: 8 lanes per token, 16 elems per lane
    const int tok = tid >> 3, seg = tid & 7;
    const size_t t = (size_t)tok0 + tok;
    float v[16];
    float s = 0.f, ss = 0.f;
    #pragma unroll
    for (int u4 = 0; u4 < 4; ++u4) {
        float4 a4 = reinterpret_cast<const float4*>(&xs[tok][seg * 16])[u4];
        float4 r4 = reinterpret_cast<const float4*>(RES + t * 128 + seg * 16)[u4];
        v[u4*4+0] = a4.x + r4.x; v[u4*4+1] = a4.y + r4.y;
        v[u4*4+2] = a4.z + r4.z; v[u4*4+3] = a4.w + r4.w;
    }
    #pragma unroll
    for (int u = 0; u < 16; ++u) { s += v[u]; ss += v[u] * v[u]; }
    #pragma unroll
    for (int st = 1; st < 8; st <<= 1) {
        s  += __shfl_xor(s, st, 8);
        ss += __shfl_xor(ss, st, 8);
    }
    float mu = s * (1.f / 128.f);
    float var = ss * (1.f / 128.f) - mu * mu;
    float rstd = rsqrtf(var + 1e-5f);
    #pragma unroll
    for (int u4 = 0; u4 < 4; ++u4) {
        float4 g4 = reinterpret_cast<const float4*>(gamma + seg * 16)[u4];
        float4 b4 = reinterpret_cast<const float4*>(beta + seg * 16)[u4];
        float4 o4;
        o4.x = (v[u4*4+0] - mu) * rstd * g4.x + b4.x;
        o4.y = (v[u4*4+1] - mu) * rstd * g4.y + b4.y;
        o4.z = (v[u4*4+2] - mu) * rstd * g4.z + b4.z;
        o4.w = (v[u4*4+3] - mu) * rstd * g4.w + b4.w;
        reinterpret_cast<float4*>(OUT + t * 128 + seg * 16)[u4] = o4;
    }
}

// ---------------- K4: gate = sigmoid(P @ Wg^T + b); OUT = P * gate (in place) ---------
__global__ __launch_bounds__(512) void gate_kernel(
    const float* __restrict__ P, const float* __restrict__ W,
    const float* __restrict__ bias, float* __restrict__ OUT)
{
    __shared__ float xs[64][132];
    __shared__ float wl[128][132];
    const int tid = threadIdx.x;
    const int tok0 = blockIdx.x * 64;

    #pragma unroll
    for (int k = 0; k < 4; ++k) {
        int f = tid + k * 512;
        int row = f >> 5, c4 = f & 31;
        float4 v = reinterpret_cast<const float4*>(P + (size_t)(tok0 + row) * DD)[c4];
        reinterpret_cast<float4*>(&xs[row][0])[c4] = v;
    }
    #pragma unroll
    for (int k = 0; k < 8; ++k) {
        int f = tid + k * 512;
        int row = f >> 5, c4 = f & 31;
        float4 v = reinterpret_cast<const float4*>(W + (size_t)row * DD)[c4];
        reinterpret_cast<float4*>(&wl[row][0])[c4] = v;
    }
    __syncthreads();

    const int eg = tid & 31, tg = tid >> 5;
    float acc[4][4] = {};
    #pragma unroll 4
    for (int d4 = 0; d4 < 32; ++d4) {
        float4 xv[4], wv[4];
        #pragma unroll
        for (int i = 0; i < 4; ++i)
            xv[i] = reinterpret_cast<const float4*>(&xs[tg + i * 16][0])[d4];
        #pragma unroll
        for (int j = 0; j < 4; ++j)
            wv[j] = reinterpret_cast<const float4*>(&wl[eg + j * 32][0])[d4];
        #pragma unroll
        for (int i = 0; i < 4; ++i)
            #pragma unroll
            for (int j = 0; j < 4; ++j)
                acc[i][j] += xv[i].x * wv[j].x + xv[i].y * wv[j].y
                           + xv[i].z * wv[j].z + xv[i].w * wv[j].w;
    }

    #pragma unroll
    for (int j = 0; j < 4; ++j) {
        int e = eg + j * 32;
        float b = bias[e];
        #pragma unroll
        for (int i = 0; i < 4; ++i) {
            float z = acc[i][j] + b;
            float g = 1.f / (1.f + __expf(-z));
            size_t t = (size_t)tok0 + tg + i * 16;
            OUT[t * 128 + e] = xs[tg + i * 16][e] * g;
        }
    }
}

extern "C" void kernel_launch(void* const* d_in, const int* in_sizes, int n_in,
                              void* d_out, int out_size, void* d_ws, size_t ws_size,
                              hipStream_t stream) {
    const float* pair    = (const float*)d_in[0];
    // d_in[1] = chain_id_tensor (unused by the reference math)
    const float* w_in_s  = (const float*)d_in[2];
    const float* b_in_s  = (const float*)d_in[3];
    const float* w_out_s = (const float*)d_in[4];
    const float* b_out_s = (const float*)d_in[5];
    const float* w_in_e  = (const float*)d_in[6];
    const float* b_in_e  = (const float*)d_in[7];
    const float* w_out_e = (const float*)d_in[8];
    const float* b_out_e = (const float*)d_in[9];
    const float* gamma_s = (const float*)d_in[10];
    const float* beta_s  = (const float*)d_in[11];
    const float* gamma_e = (const float*)d_in[12];
    const float* beta_e  = (const float*)d_in[13];
    const float* w_gate  = (const float*)d_in[14];
    const float* b_gate  = (const float*)d_in[15];
    float* out = (float*)d_out;

    // workspace: qkv bf16 [65536][384] (48 MiB) + attn bf16 [65536][128] (16 MiB)
    __hip_bfloat16* qkv  = (__hip_bfloat16*)d_ws;
    __hip_bfloat16* attn = qkv + (size_t)65536 * 384;

    // ---- phase 1: row-wise (starting node) attention ----
    proj_qkv_kernel<<<1024, 512, 0, stream>>>(pair, w_in_s, b_in_s, qkv, 0);
    attn_kernel<<<dim3(4, 4, 256), 512, 0, stream>>>(qkv, attn);
    proj_ln_kernel<<<1024, 512, 0, stream>>>(attn, w_out_s, b_out_s, pair,
                                             gamma_s, beta_s, out, 0);
    // ---- phase 2: column-wise (ending node) attention, transposed layout ----
    proj_qkv_kernel<<<1024, 512, 0, stream>>>(out, w_in_e, b_in_e, qkv, 1);
    attn_kernel<<<dim3(4, 4, 256), 512, 0, stream>>>(qkv, attn);
    proj_ln_kernel<<<1024, 512, 0, stream>>>(attn, w_out_e, b_out_e, out,
                                             gamma_e, beta_e, out, 1);
    // ---- gate ----
    gate_kernel<<<1024, 512, 0, stream>>>(out, w_gate, b_gate, out);
}

// Round 2
// 467.126 us; speedup vs baseline: 1.7345x; 1.7345x over previous
//
#include <hip/hip_runtime.h>
#include <hip/hip_bf16.h>
#include <cstddef>

// Problem constants: B=1, L=256, D=128, H=4, hd=32
#define DD 128

typedef unsigned short u16;
typedef short short8v __attribute__((ext_vector_type(8)));   // 8 bf16 (4 VGPRs)
typedef float floatx4 __attribute__((ext_vector_type(4)));   // 4 fp32 acc

__device__ __forceinline__ float bf2f(u16 u) {
    return __uint_as_float(((unsigned int)u) << 16);
}
__device__ __forceinline__ u16 f2b(float x) {   // round-to-nearest-even f32->bf16
    unsigned u = __float_as_uint(x);
    return (u16)((u + 0x7FFF + ((u >> 16) & 1)) >> 16);
}

// ---------------- K1: QKV projection (fp32 VALU, unchanged) ----------------
__global__ __launch_bounds__(512) void proj_qkv_kernel(
    const float* __restrict__ X, const float* __restrict__ W,
    const float* __restrict__ bias, __hip_bfloat16* __restrict__ Y,
    int transposed)
{
    __shared__ float xs[64][132];
    __shared__ float wl[128][132];
    const int tid = threadIdx.x;
    const int tok0 = blockIdx.x * 64;

    #pragma unroll
    for (int k = 0; k < 4; ++k) {
        int f = tid + k * 512;
        int row = f >> 5, c4 = f & 31;
        int t = tok0 + row;
        int xrow = transposed ? ((t & 255) * 256 + (t >> 8)) : t;
        float4 v = reinterpret_cast<const float4*>(X + (size_t)xrow * DD)[c4];
        reinterpret_cast<float4*>(&xs[row][0])[c4] = v;
    }

    const int eg = tid & 31;
    const int tg = tid >> 5;

    for (int c = 0; c < 3; ++c) {
        __syncthreads();
        #pragma unroll
        for (int k = 0; k < 8; ++k) {
            int f = tid + k * 512;
            int row = f >> 5, c4 = f & 31;
            float4 v = reinterpret_cast<const float4*>(W + (size_t)(c * 128 + row) * DD)[c4];
            reinterpret_cast<float4*>(&wl[row][0])[c4] = v;
        }
        __syncthreads();

        float acc[4][4] = {};
        #pragma unroll 4
        for (int d4 = 0; d4 < 32; ++d4) {
            float4 xv[4], wv[4];
            #pragma unroll
            for (int i = 0; i < 4; ++i)
                xv[i] = reinterpret_cast<const float4*>(&xs[tg + i * 16][0])[d4];
            #pragma unroll
            for (int j = 0; j < 4; ++j)
                wv[j] = reinterpret_cast<const float4*>(&wl[eg + j * 32][0])[d4];
            #pragma unroll
            for (int i = 0; i < 4; ++i)
                #pragma unroll
                for (int j = 0; j < 4; ++j)
                    acc[i][j] += xv[i].x * wv[j].x + xv[i].y * wv[j].y
                               + xv[i].z * wv[j].z + xv[i].w * wv[j].w;
        }

        #pragma unroll
        for (int j = 0; j < 4; ++j) {
            int e = c * 128 + eg + j * 32;
            float b = bias[e];
            #pragma unroll
            for (int i = 0; i < 4; ++i) {
                int t = tok0 + tg + i * 16;
                Y[(size_t)t * 384 + e] = __float2bfloat16(acc[i][j] + b);
            }
        }
    }
}

// ---------------- K2: MFMA attention, one block per (head, row) ----------------
// QKV layout: [256 rows][256 seq][384] bf16; q at [0,128), k at [128,256), v at [256,384)
// O layout:   [256 rows][256 seq][128] bf16
// 256 threads = 4 waves; wave w owns queries [w*64, w*64+64).
// Scores computed swapped: S^T[k][q] = mfma(A=K_frag, B=Q_frag); softmax over k is
// lane-local regs + shfl_xor(16/32). P written to per-wave LDS (4 consecutive k / lane).
// PV computed as O^T[d][q] = mfma(A=Vt_frag, B=P_frag) accumulated over 8 k-steps.
__global__ __launch_bounds__(256) void attn_mfma_kernel(
    const __hip_bfloat16* __restrict__ QKV, __hip_bfloat16* __restrict__ O)
{
    constexpr int KP = 40;    // K_lds row pitch (u16): 80 B, 16B-aligned, bank-spread
    constexpr int PP = 264;   // Vt/P row pitch (u16): 528 B
    __shared__ u16 K_lds[256 * KP];      // 20480 B
    __shared__ u16 Vt_lds[32 * PP];      // 16896 B
    __shared__ u16 P_lds[4 * 16 * PP];   // 33792 B  (per-wave 16 x 264)

    const int tid = threadIdx.x;
    const int h = blockIdx.x, r = blockIdx.y;
    const u16* q16 = reinterpret_cast<const u16*>(QKV);
    const size_t base = (size_t)r * 256 * 384;

    // ---- stage K row-major: 256 x 32 u16 as 1024 16B chunks ----
    #pragma unroll
    for (int it = 0; it < 4; ++it) {
        int f = tid + it * 256;
        int row = f >> 2, c = f & 3;
        uint4 v = *reinterpret_cast<const uint4*>(q16 + base + (size_t)row * 384 + 128 + h * 32 + c * 8);
        *reinterpret_cast<uint4*>(&K_lds[row * KP + c * 8]) = v;
    }
    // ---- stage V transposed: Vt[d][k]; thread = (d-quad, k-octet) ----
    {
        int dq = tid & 7, ko = tid >> 3;
        int k0 = ko * 8;
        ushort4 col[8];
        #pragma unroll
        for (int j = 0; j < 8; ++j)
            col[j] = *reinterpret_cast<const ushort4*>(
                q16 + base + (size_t)(k0 + j) * 384 + 256 + h * 32 + dq * 4);
        #pragma unroll
        for (int dd = 0; dd < 4; ++dd) {
            u16 vals[8];
            #pragma unroll
            for (int j = 0; j < 8; ++j) vals[j] = reinterpret_cast<const u16*>(&col[j])[dd];
            *reinterpret_cast<uint4*>(&Vt_lds[(dq * 4 + dd) * PP + k0]) =
                *reinterpret_cast<const uint4*>(vals);
        }
    }
    __syncthreads();

    const int lane = tid & 63;
    const int wq = tid >> 6;          // wave id: queries [wq*64, wq*64+64)
    const int lq = lane & 15;
    const int g  = lane >> 4;         // 0..3

    // preload Vt A-fragments: A[m=d][kk], lane: d = md*16+lq, kk = ks*32 + g*8 + j
    short8v vfrag[2][8];
    #pragma unroll
    for (int md = 0; md < 2; ++md)
        #pragma unroll
        for (int ks = 0; ks < 8; ++ks)
            vfrag[md][ks] = *reinterpret_cast<const short8v*>(
                &Vt_lds[(md * 16 + lq) * PP + ks * 32 + g * 8]);

    u16* myP = &P_lds[wq * 16 * PP];
    const float SCALE = 0.17677669529663687f;  // 1/sqrt(32)

    for (int mq = 0; mq < 4; ++mq) {
        const int q0 = wq * 64 + mq * 16;
        // Q B-fragment from global: B[d][q], lane: q = lq, d = g*8 + j
        short8v qfrag = *reinterpret_cast<const short8v*>(
            q16 + base + (size_t)(q0 + lq) * 384 + h * 32 + g * 8);

        // scores: S^T[k][q]; s[ni][rr] = S[k = ni*16 + g*4 + rr][q0 + lq]
        floatx4 s[16];
        #pragma unroll
        for (int ni = 0; ni < 16; ++ni) {
            short8v kfrag = *reinterpret_cast<const short8v*>(&K_lds[(ni * 16 + lq) * KP + g * 8]);
            floatx4 z = {0.f, 0.f, 0.f, 0.f};
            s[ni] = __builtin_amdgcn_mfma_f32_16x16x32_bf16(kfrag, qfrag, z, 0, 0, 0);
        }

        // softmax over k for this lane's q
        float m = -1e30f;
        #pragma unroll
        for (int ni = 0; ni < 16; ++ni)
            m = fmaxf(fmaxf(fmaxf(m, s[ni][0]), fmaxf(s[ni][1], s[ni][2])), s[ni][3]);
        m = fmaxf(m, __shfl_xor(m, 16));
        m = fmaxf(m, __shfl_xor(m, 32));

        float ell = 0.f;
        #pragma unroll
        for (int ni = 0; ni < 16; ++ni) {
            float p0 = __expf((s[ni][0] - m) * SCALE);
            float p1 = __expf((s[ni][1] - m) * SCALE);
            float p2 = __expf((s[ni][2] - m) * SCALE);
            float p3 = __expf((s[ni][3] - m) * SCALE);
            ell += (p0 + p1) + (p2 + p3);
            ushort4 pk;
            pk.x = f2b(p0); pk.y = f2b(p1); pk.z = f2b(p2); pk.w = f2b(p3);
            *reinterpret_cast<ushort4*>(&myP[lq * PP + ni * 16 + g * 4]) = pk;
        }
        ell += __shfl_xor(ell, 16);
        ell += __shfl_xor(ell, 32);

        __syncthreads();   // P writes visible (and waves aligned)

        // PV: O^T[d][q] += Vt_frag * P_frag over 8 k-steps
        floatx4 o0 = {0.f, 0.f, 0.f, 0.f}, o1 = {0.f, 0.f, 0.f, 0.f};
        #pragma unroll
        for (int ks = 0; ks < 8; ++ks) {
            short8v pfrag = *reinterpret_cast<const short8v*>(&myP[lq * PP + ks * 32 + g * 8]);
            o0 = __builtin_amdgcn_mfma_f32_16x16x32_bf16(vfrag[0][ks], pfrag, o0, 0, 0, 0);
            o1 = __builtin_amdgcn_mfma_f32_16x16x32_bf16(vfrag[1][ks], pfrag, o1, 0, 0, 0);
        }

        const float inv = 1.f / ell;
        // D[row=d][col=q]: d = md*16 + g*4 + rr, q = q0 + lq -> 4 consecutive d per lane
        __hip_bfloat16* orow = O + ((size_t)r * 256 + q0 + lq) * 128 + h * 32;
        ushort4 w0, w1;
        w0.x = f2b(o0[0] * inv); w0.y = f2b(o0[1] * inv);
        w0.z = f2b(o0[2] * inv); w0.w = f2b(o0[3] * inv);
        w1.x = f2b(o1[0] * inv); w1.y = f2b(o1[1] * inv);
        w1.z = f2b(o1[2] * inv); w1.w = f2b(o1[3] * inv);
        *reinterpret_cast<ushort4*>(reinterpret_cast<u16*>(orow) + g * 4) = w0;
        *reinterpret_cast<ushort4*>(reinterpret_cast<u16*>(orow) + 16 + g * 4) = w1;

        __syncthreads();   // protect P from next iteration's writes
    }
}

// ---------------- K3: out-projection + bias + residual + LayerNorm (unchanged) ------
__global__ __launch_bounds__(512) void proj_ln_kernel(
    const __hip_bfloat16* __restrict__ A, const float* __restrict__ W,
    const float* __restrict__ bias, const float* __restrict__ RES,
    const float* __restrict__ gamma, const float* __restrict__ beta,
    float* __restrict__ OUT, int transposed)
{
    __shared__ float xs[64][132];
    __shared__ float wl[128][132];
    const int tid = threadIdx.x;
    const int tok0 = blockIdx.x * 64;
    const u16* A16 = reinterpret_cast<const u16*>(A);

    #pragma unroll
    for (int k = 0; k < 4; ++k) {
        int f = tid + k * 512;
        int row = f >> 5, q4 = f & 31;
        int t = tok0 + row;
        int arow = transposed ? ((t & 255) * 256 + (t >> 8)) : t;
        ushort4 u = *reinterpret_cast<const ushort4*>(A16 + (size_t)arow * 128 + q4 * 4);
        xs[row][q4*4+0] = bf2f(u.x); xs[row][q4*4+1] = bf2f(u.y);
        xs[row][q4*4+2] = bf2f(u.z); xs[row][q4*4+3] = bf2f(u.w);
    }
    #pragma unroll
    for (int k = 0; k < 8; ++k) {
        int f = tid + k * 512;
        int row = f >> 5, q4 = f & 31;
        float4 v = reinterpret_cast<const float4*>(W + (size_t)row * DD)[q4];
        reinterpret_cast<float4*>(&wl[row][0])[q4] = v;
    }
    __syncthreads();

    const int eg = tid & 31, tg = tid >> 5;
    float acc[4][4] = {};
    #pragma unroll 4
    for (int d4 = 0; d4 < 32; ++d4) {
        float4 xv[4], wv[4];
        #pragma unroll
        for (int i = 0; i < 4; ++i)
            xv[i] = reinterpret_cast<const float4*>(&xs[tg + i * 16][0])[d4];
        #pragma unroll
        for (int j = 0; j < 4; ++j)
            wv[j] = reinterpret_cast<const float4*>(&wl[eg + j * 32][0])[d4];
        #pragma unroll
        for (int i = 0; i < 4; ++i)
            #pragma unroll
            for (int j = 0; j < 4; ++j)
                acc[i][j] += xv[i].x * wv[j].x + xv[i].y * wv[j].y
                           + xv[i].z * wv[j].z + xv[i].w * wv[j].w;
    }
    __syncthreads();
    #pragma unroll
    for (int j = 0; j < 4; ++j) {
        float b = bias[eg + j * 32];
        #pragma unroll
        for (int i = 0; i < 4; ++i)
            xs[tg + i * 16][eg + j * 32] = acc[i][j] + b;
    }
    __syncthreads();

    const int tok = tid >> 3, seg = tid & 7;
    const size_t t = (size_t)tok0 + tok;
    float v[16];
    float s = 0.f, ss = 0.f;
    #pragma unroll
    for (int u4 = 0; u4 < 4; ++u4) {
        float4 a4 = reinterpret_cast<const float4*>(&xs[tok][seg * 16])[u4];
        float4 r4 = reinterpret_cast<const float4*>(RES + t * 128 + seg * 16)[u4];
        v[u4*4+0] = a4.x + r4.x; v[u4*4+1] = a4.y + r4.y;
        v[u4*4+2] = a4.z + r4.z; v[u4*4+3] = a4.w + r4.w;
    }
    #pragma unroll
    for (int u = 0; u < 16; ++u) { s += v[u]; ss += v[u] * v[u]; }
    #pragma unroll
    for (int st = 1; st < 8; st <<= 1) {
        s  += __shfl_xor(s, st, 8);
        ss += __shfl_xor(ss, st, 8);
    }
    float mu = s * (1.f / 128.f);
    float var = ss * (1.f / 128.f) - mu * mu;
    float rstd = rsqrtf(var + 1e-5f);
    #pragma unroll
    for (int u4 = 0; u4 < 4; ++u4) {
        float4 g4 = reinterpret_cast<const float4*>(gamma + seg * 16)[u4];
        float4 b4 = reinterpret_cast<const float4*>(beta + seg * 16)[u4];
        float4 o4;
        o4.x = (v[u4*4+0] - mu) * rstd * g4.x + b4.x;
        o4.y = (v[u4*4+1] - mu) * rstd * g4.y + b4.y;
        o4.z = (v[u4*4+2] - mu) * rstd * g4.z + b4.z;
        o4.w = (v[u4*4+3] - mu) * rstd * g4.w + b4.w;
        reinterpret_cast<float4*>(OUT + t * 128 + seg * 16)[u4] = o4;
    }
}

// ---------------- K4: gate (unchanged) ----------------
__global__ __launch_bounds__(512) void gate_kernel(
    const float* __restrict__ P, const float* __restrict__ W,
    const float* __restrict__ bias, float* __restrict__ OUT)
{
    __shared__ float xs[64][132];
    __shared__ float wl[128][132];
    const int tid = threadIdx.x;
    const int tok0 = blockIdx.x * 64;

    #pragma unroll
    for (int k = 0; k < 4; ++k) {
        int f = tid + k * 512;
        int row = f >> 5, c4 = f & 31;
        float4 v = reinterpret_cast<const float4*>(P + (size_t)(tok0 + row) * DD)[c4];
        reinterpret_cast<float4*>(&xs[row][0])[c4] = v;
    }
    #pragma unroll
    for (int k = 0; k < 8; ++k) {
        int f = tid + k * 512;
        int row = f >> 5, c4 = f & 31;
        float4 v = reinterpret_cast<const float4*>(W + (size_t)row * DD)[c4];
        reinterpret_cast<float4*>(&wl[row][0])[c4] = v;
    }
    __syncthreads();

    const int eg = tid & 31, tg = tid >> 5;
    float acc[4][4] = {};
    #pragma unroll 4
    for (int d4 = 0; d4 < 32; ++d4) {
        float4 xv[4], wv[4];
        #pragma unroll
        for (int i = 0; i < 4; ++i)
            xv[i] = reinterpret_cast<const float4*>(&xs[tg + i * 16][0])[d4];
        #pragma unroll
        for (int j = 0; j < 4; ++j)
            wv[j] = reinterpret_cast<const float4*>(&wl[eg + j * 32][0])[d4];
        #pragma unroll
        for (int i = 0; i < 4; ++i)
            #pragma unroll
            for (int j = 0; j < 4; ++j)
                acc[i][j] += xv[i].x * wv[j].x + xv[i].y * wv[j].y
                           + xv[i].z * wv[j].z + xv[i].w * wv[j].w;
    }

    #pragma unroll
    for (int j = 0; j < 4; ++j) {
        int e = eg + j * 32;
        float b = bias[e];
        #pragma unroll
        for (int i = 0; i < 4; ++i) {
            float z = acc[i][j] + b;
            float gt = 1.f / (1.f + __expf(-z));
            size_t t = (size_t)tok0 + tg + i * 16;
            OUT[t * 128 + e] = xs[tg + i * 16][e] * gt;
        }
    }
}

extern "C" void kernel_launch(void* const* d_in, const int* in_sizes, int n_in,
                              void* d_out, int out_size, void* d_ws, size_t ws_size,
                              hipStream_t stream) {
    const float* pair    = (const float*)d_in[0];
    const float* w_in_s  = (const float*)d_in[2];
    const float* b_in_s  = (const float*)d_in[3];
    const float* w_out_s = (const float*)d_in[4];
    const float* b_out_s = (const float*)d_in[5];
    const float* w_in_e  = (const float*)d_in[6];
    const float* b_in_e  = (const float*)d_in[7];
    const float* w_out_e = (const float*)d_in[8];
    const float* b_out_e = (const float*)d_in[9];
    const float* gamma_s = (const float*)d_in[10];
    const float* beta_s  = (const float*)d_in[11];
    const float* gamma_e = (const float*)d_in[12];
    const float* beta_e  = (const float*)d_in[13];
    const float* w_gate  = (const float*)d_in[14];
    const float* b_gate  = (const float*)d_in[15];
    float* out = (float*)d_out;

    __hip_bfloat16* qkv  = (__hip_bfloat16*)d_ws;
    __hip_bfloat16* attn = qkv + (size_t)65536 * 384;

    // ---- phase 1: row-wise (starting node) attention ----
    proj_qkv_kernel<<<1024, 512, 0, stream>>>(pair, w_in_s, b_in_s, qkv, 0);
    attn_mfma_kernel<<<dim3(4, 256), 256, 0, stream>>>(qkv, attn);
    proj_ln_kernel<<<1024, 512, 0, stream>>>(attn, w_out_s, b_out_s, pair,
                                             gamma_s, beta_s, out, 0);
    // ---- phase 2: column-wise (ending node) attention, transposed layout ----
    proj_qkv_kernel<<<1024, 512, 0, stream>>>(out, w_in_e, b_in_e, qkv, 1);
    attn_mfma_kernel<<<dim3(4, 256), 256, 0, stream>>>(qkv, attn);
    proj_ln_kernel<<<1024, 512, 0, stream>>>(attn, w_out_e, b_out_e, out,
                                             gamma_e, beta_e, out, 1);
    // ---- gate ----
    gate_kernel<<<1024, 512, 0, stream>>>(out, w_gate, b_gate, out);
}

// Round 3
// 185.863 us; speedup vs baseline: 4.3593x; 2.5133x over previous
//
#include <hip/hip_runtime.h>
#include <hip/hip_bf16.h>
#include <cstddef>

// Problem constants: B=1, L=256, D=128, H=4, hd=32
#define DD 128

typedef unsigned short u16;
typedef short short8v __attribute__((ext_vector_type(8)));   // 8 bf16 (4 VGPRs)
typedef float floatx4 __attribute__((ext_vector_type(4)));   // 4 fp32 acc

__device__ __forceinline__ float bf2f(u16 u) {
    return __uint_as_float(((unsigned int)u) << 16);
}
__device__ __forceinline__ u16 f2b(float x) {   // round-to-nearest-even f32->bf16
    unsigned u = __float_as_uint(x);
    return (u16)((u + 0x7FFF + ((u >> 16) & 1)) >> 16);
}

// Stage a 128x128 fp32 weight block into LDS as bf16, pitch 136 u16 (272 B).
// Pitch 136: ds_read_b128 at (row*136 + g*8)*2 B -> slot (lq+g) mod 8, uniform.
__device__ __forceinline__ void stage_w_bf16(const float* __restrict__ Wf,
                                             u16* __restrict__ Wl, int tid) {
    #pragma unroll
    for (int it = 0; it < 8; ++it) {
        int f = tid + it * 512;           // 4096 float4 chunks
        int row = f >> 5, c4 = f & 31;
        float4 v = reinterpret_cast<const float4*>(Wf + (size_t)row * DD)[c4];
        ushort4 o;
        o.x = f2b(v.x); o.y = f2b(v.y); o.z = f2b(v.z); o.w = f2b(v.w);
        *reinterpret_cast<ushort4*>(&Wl[row * 136 + c4 * 4]) = o;
    }
}

// ---------------- K1: QKV projection, MFMA ----------------
// Y[t][e] = sum_d X[t][d]*W[e][d] + bias[e], e in [0,384). Y bf16 [65536][384].
// Block: 128 tokens, 8 waves (16 tokens each). W processed in 3 chunks of 128 rows.
__global__ __launch_bounds__(512) void proj_qkv_mfma(
    const float* __restrict__ X, const float* __restrict__ Wf,
    const float* __restrict__ bias, __hip_bfloat16* __restrict__ Y,
    int transposed)
{
    __shared__ u16 Wl[128 * 136];   // 34816 B
    const int tid = threadIdx.x;
    const int tok0 = blockIdx.x * 128;
    const int lane = tid & 63, wq = tid >> 6;
    const int lq = lane & 15, g = lane >> 4;
    const int t = tok0 + wq * 16 + lq;
    const int xrow = transposed ? ((t & 255) * 256 + (t >> 8)) : t;

    // B-fragments: X[t][ks*32 + g*8 + j], fp32 -> bf16, once per lane
    short8v bfrag[4];
    #pragma unroll
    for (int ks = 0; ks < 4; ++ks) {
        const float* p = X + (size_t)xrow * DD + ks * 32 + g * 8;
        float4 a = *reinterpret_cast<const float4*>(p);
        float4 b = *reinterpret_cast<const float4*>(p + 4);
        u16 tmp[8] = { f2b(a.x), f2b(a.y), f2b(a.z), f2b(a.w),
                       f2b(b.x), f2b(b.y), f2b(b.z), f2b(b.w) };
        bfrag[ks] = *reinterpret_cast<const short8v*>(tmp);
    }

    u16* Yt = reinterpret_cast<u16*>(Y) + (size_t)t * 384;

    for (int c = 0; c < 3; ++c) {
        if (c) __syncthreads();                 // Wl reuse guard
        stage_w_bf16(Wf + (size_t)c * 128 * DD, Wl, tid);
        __syncthreads();
        #pragma unroll
        for (int et = 0; et < 8; ++et) {
            float4 b4 = *reinterpret_cast<const float4*>(bias + c * 128 + et * 16 + g * 4);
            floatx4 acc = { b4.x, b4.y, b4.z, b4.w };
            #pragma unroll
            for (int ks = 0; ks < 4; ++ks) {
                short8v afrag = *reinterpret_cast<const short8v*>(
                    &Wl[(et * 16 + lq) * 136 + ks * 32 + g * 8]);
                acc = __builtin_amdgcn_mfma_f32_16x16x32_bf16(afrag, bfrag[ks], acc, 0, 0, 0);
            }
            ushort4 o;
            o.x = f2b(acc[0]); o.y = f2b(acc[1]); o.z = f2b(acc[2]); o.w = f2b(acc[3]);
            *reinterpret_cast<ushort4*>(&Yt[c * 128 + et * 16 + g * 4]) = o;
        }
    }
}

// ---------------- K2: MFMA attention, one block per (head, row) (unchanged) -------
__global__ __launch_bounds__(256) void attn_mfma_kernel(
    const __hip_bfloat16* __restrict__ QKV, __hip_bfloat16* __restrict__ O)
{
    constexpr int KP = 40;
    constexpr int PP = 264;
    __shared__ u16 K_lds[256 * KP];
    __shared__ u16 Vt_lds[32 * PP];
    __shared__ u16 P_lds[4 * 16 * PP];

    const int tid = threadIdx.x;
    const int h = blockIdx.x, r = blockIdx.y;
    const u16* q16 = reinterpret_cast<const u16*>(QKV);
    const size_t base = (size_t)r * 256 * 384;

    #pragma unroll
    for (int it = 0; it < 4; ++it) {
        int f = tid + it * 256;
        int row = f >> 2, c = f & 3;
        uint4 v = *reinterpret_cast<const uint4*>(q16 + base + (size_t)row * 384 + 128 + h * 32 + c * 8);
        *reinterpret_cast<uint4*>(&K_lds[row * KP + c * 8]) = v;
    }
    {
        int dq = tid & 7, ko = tid >> 3;
        int k0 = ko * 8;
        ushort4 col[8];
        #pragma unroll
        for (int j = 0; j < 8; ++j)
            col[j] = *reinterpret_cast<const ushort4*>(
                q16 + base + (size_t)(k0 + j) * 384 + 256 + h * 32 + dq * 4);
        #pragma unroll
        for (int dd = 0; dd < 4; ++dd) {
            u16 vals[8];
            #pragma unroll
            for (int j = 0; j < 8; ++j) vals[j] = reinterpret_cast<const u16*>(&col[j])[dd];
            *reinterpret_cast<uint4*>(&Vt_lds[(dq * 4 + dd) * PP + k0]) =
                *reinterpret_cast<const uint4*>(vals);
        }
    }
    __syncthreads();

    const int lane = tid & 63;
    const int wq = tid >> 6;
    const int lq = lane & 15;
    const int g  = lane >> 4;

    short8v vfrag[2][8];
    #pragma unroll
    for (int md = 0; md < 2; ++md)
        #pragma unroll
        for (int ks = 0; ks < 8; ++ks)
            vfrag[md][ks] = *reinterpret_cast<const short8v*>(
                &Vt_lds[(md * 16 + lq) * PP + ks * 32 + g * 8]);

    u16* myP = &P_lds[wq * 16 * PP];
    const float SCALE = 0.17677669529663687f;

    for (int mq = 0; mq < 4; ++mq) {
        const int q0 = wq * 64 + mq * 16;
        short8v qfrag = *reinterpret_cast<const short8v*>(
            q16 + base + (size_t)(q0 + lq) * 384 + h * 32 + g * 8);

        floatx4 s[16];
        #pragma unroll
        for (int ni = 0; ni < 16; ++ni) {
            short8v kfrag = *reinterpret_cast<const short8v*>(&K_lds[(ni * 16 + lq) * KP + g * 8]);
            floatx4 z = {0.f, 0.f, 0.f, 0.f};
            s[ni] = __builtin_amdgcn_mfma_f32_16x16x32_bf16(kfrag, qfrag, z, 0, 0, 0);
        }

        float m = -1e30f;
        #pragma unroll
        for (int ni = 0; ni < 16; ++ni)
            m = fmaxf(fmaxf(fmaxf(m, s[ni][0]), fmaxf(s[ni][1], s[ni][2])), s[ni][3]);
        m = fmaxf(m, __shfl_xor(m, 16));
        m = fmaxf(m, __shfl_xor(m, 32));

        float ell = 0.f;
        #pragma unroll
        for (int ni = 0; ni < 16; ++ni) {
            float p0 = __expf((s[ni][0] - m) * SCALE);
            float p1 = __expf((s[ni][1] - m) * SCALE);
            float p2 = __expf((s[ni][2] - m) * SCALE);
            float p3 = __expf((s[ni][3] - m) * SCALE);
            ell += (p0 + p1) + (p2 + p3);
            ushort4 pk;
            pk.x = f2b(p0); pk.y = f2b(p1); pk.z = f2b(p2); pk.w = f2b(p3);
            *reinterpret_cast<ushort4*>(&myP[lq * PP + ni * 16 + g * 4]) = pk;
        }
        ell += __shfl_xor(ell, 16);
        ell += __shfl_xor(ell, 32);

        __syncthreads();

        floatx4 o0 = {0.f, 0.f, 0.f, 0.f}, o1 = {0.f, 0.f, 0.f, 0.f};
        #pragma unroll
        for (int ks = 0; ks < 8; ++ks) {
            short8v pfrag = *reinterpret_cast<const short8v*>(&myP[lq * PP + ks * 32 + g * 8]);
            o0 = __builtin_amdgcn_mfma_f32_16x16x32_bf16(vfrag[0][ks], pfrag, o0, 0, 0, 0);
            o1 = __builtin_amdgcn_mfma_f32_16x16x32_bf16(vfrag[1][ks], pfrag, o1, 0, 0, 0);
        }

        const float inv = 1.f / ell;
        __hip_bfloat16* orow = O + ((size_t)r * 256 + q0 + lq) * 128 + h * 32;
        ushort4 w0, w1;
        w0.x = f2b(o0[0] * inv); w0.y = f2b(o0[1] * inv);
        w0.z = f2b(o0[2] * inv); w0.w = f2b(o0[3] * inv);
        w1.x = f2b(o1[0] * inv); w1.y = f2b(o1[1] * inv);
        w1.z = f2b(o1[2] * inv); w1.w = f2b(o1[3] * inv);
        *reinterpret_cast<ushort4*>(reinterpret_cast<u16*>(orow) + g * 4) = w0;
        *reinterpret_cast<ushort4*>(reinterpret_cast<u16*>(orow) + 16 + g * 4) = w1;

        __syncthreads();
    }
}

// ---------------- K3: out-projection + bias + residual + LayerNorm, MFMA ----------
// OUT[t] = LN( RES[t] + A[arow(t)] @ W^T + bias ); LN reduce across 4 g-lanes.
__global__ __launch_bounds__(512) void proj_ln_mfma(
    const __hip_bfloat16* __restrict__ A, const float* __restrict__ Wf,
    const float* __restrict__ bias, const float* __restrict__ RES,
    const float* __restrict__ gamma, const float* __restrict__ beta,
    float* __restrict__ OUT, int transposed)
{
    __shared__ u16 Wl[128 * 136];
    const int tid = threadIdx.x;
    const int tok0 = blockIdx.x * 128;
    const int lane = tid & 63, wq = tid >> 6;
    const int lq = lane & 15, g = lane >> 4;
    const int t = tok0 + wq * 16 + lq;
    const int arow = transposed ? ((t & 255) * 256 + (t >> 8)) : t;
    const u16* A16 = reinterpret_cast<const u16*>(A);

    stage_w_bf16(Wf, Wl, tid);

    short8v bfrag[4];
    #pragma unroll
    for (int ks = 0; ks < 4; ++ks)
        bfrag[ks] = *reinterpret_cast<const short8v*>(A16 + (size_t)arow * DD + ks * 32 + g * 8);

    __syncthreads();

    floatx4 acc[8];
    #pragma unroll
    for (int et = 0; et < 8; ++et) {
        float4 b4 = *reinterpret_cast<const float4*>(bias + et * 16 + g * 4);
        float4 r4 = *reinterpret_cast<const float4*>(RES + (size_t)t * DD + et * 16 + g * 4);
        acc[et] = { b4.x + r4.x, b4.y + r4.y, b4.z + r4.z, b4.w + r4.w };
        #pragma unroll
        for (int ks = 0; ks < 4; ++ks) {
            short8v afrag = *reinterpret_cast<const short8v*>(
                &Wl[(et * 16 + lq) * 136 + ks * 32 + g * 8]);
            acc[et] = __builtin_amdgcn_mfma_f32_16x16x32_bf16(afrag, bfrag[ks], acc[et], 0, 0, 0);
        }
    }

    // LayerNorm: token t's 128 values live across g-lanes (lq, lq+16, lq+32, lq+48)
    float s = 0.f, ss = 0.f;
    #pragma unroll
    for (int et = 0; et < 8; ++et)
        #pragma unroll
        for (int rr = 0; rr < 4; ++rr) { float v = acc[et][rr]; s += v; ss += v * v; }
    s  += __shfl_xor(s, 16);  s  += __shfl_xor(s, 32);
    ss += __shfl_xor(ss, 16); ss += __shfl_xor(ss, 32);
    float mu = s * (1.f / 128.f);
    float var = ss * (1.f / 128.f) - mu * mu;
    float rstd = rsqrtf(var + 1e-5f);

    #pragma unroll
    for (int et = 0; et < 8; ++et) {
        float4 g4 = *reinterpret_cast<const float4*>(gamma + et * 16 + g * 4);
        float4 be4 = *reinterpret_cast<const float4*>(beta + et * 16 + g * 4);
        float4 o4;
        o4.x = (acc[et][0] - mu) * rstd * g4.x + be4.x;
        o4.y = (acc[et][1] - mu) * rstd * g4.y + be4.y;
        o4.z = (acc[et][2] - mu) * rstd * g4.z + be4.z;
        o4.w = (acc[et][3] - mu) * rstd * g4.w + be4.w;
        *reinterpret_cast<float4*>(OUT + (size_t)t * DD + et * 16 + g * 4) = o4;
    }
}

// ---------------- K4: gate, MFMA; OUT = P * sigmoid(P@Wg^T + b) in place ----------
__global__ __launch_bounds__(512) void gate_mfma(
    const float* __restrict__ P, const float* __restrict__ Wf,
    const float* __restrict__ bias, float* __restrict__ OUT)
{
    __shared__ u16 Wl[128 * 136];
    const int tid = threadIdx.x;
    const int tok0 = blockIdx.x * 128;
    const int lane = tid & 63, wq = tid >> 6;
    const int lq = lane & 15, g = lane >> 4;
    const int t = tok0 + wq * 16 + lq;

    stage_w_bf16(Wf, Wl, tid);

    short8v bfrag[4];
    #pragma unroll
    for (int ks = 0; ks < 4; ++ks) {
        const float* p = P + (size_t)t * DD + ks * 32 + g * 8;
        float4 a = *reinterpret_cast<const float4*>(p);
        float4 b = *reinterpret_cast<const float4*>(p + 4);
        u16 tmp[8] = { f2b(a.x), f2b(a.y), f2b(a.z), f2b(a.w),
                       f2b(b.x), f2b(b.y), f2b(b.z), f2b(b.w) };
        bfrag[ks] = *reinterpret_cast<const short8v*>(tmp);
    }

    __syncthreads();

    floatx4 acc[8];
    #pragma unroll
    for (int et = 0; et < 8; ++et) {
        float4 b4 = *reinterpret_cast<const float4*>(bias + et * 16 + g * 4);
        acc[et] = { b4.x, b4.y, b4.z, b4.w };
        #pragma unroll
        for (int ks = 0; ks < 4; ++ks) {
            short8v afrag = *reinterpret_cast<const short8v*>(
                &Wl[(et * 16 + lq) * 136 + ks * 32 + g * 8]);
            acc[et] = __builtin_amdgcn_mfma_f32_16x16x32_bf16(afrag, bfrag[ks], acc[et], 0, 0, 0);
        }
    }

    // load P slices first (all reads before this lane's writes; slice ownership
    // for store-indexing equals reload-indexing -> race-free in place)
    float4 pv[8];
    #pragma unroll
    for (int et = 0; et < 8; ++et)
        pv[et] = *reinterpret_cast<const float4*>(P + (size_t)t * DD + et * 16 + g * 4);

    #pragma unroll
    for (int et = 0; et < 8; ++et) {
        float4 o4;
        o4.x = pv[et].x / (1.f + __expf(-acc[et][0]));
        o4.y = pv[et].y / (1.f + __expf(-acc[et][1]));
        o4.z = pv[et].z / (1.f + __expf(-acc[et][2]));
        o4.w = pv[et].w / (1.f + __expf(-acc[et][3]));
        *reinterpret_cast<float4*>(OUT + (size_t)t * DD + et * 16 + g * 4) = o4;
    }
}

extern "C" void kernel_launch(void* const* d_in, const int* in_sizes, int n_in,
                              void* d_out, int out_size, void* d_ws, size_t ws_size,
                              hipStream_t stream) {
    const float* pair    = (const float*)d_in[0];
    const float* w_in_s  = (const float*)d_in[2];
    const float* b_in_s  = (const float*)d_in[3];
    const float* w_out_s = (const float*)d_in[4];
    const float* b_out_s = (const float*)d_in[5];
    const float* w_in_e  = (const float*)d_in[6];
    const float* b_in_e  = (const float*)d_in[7];
    const float* w_out_e = (const float*)d_in[8];
    const float* b_out_e = (const float*)d_in[9];
    const float* gamma_s = (const float*)d_in[10];
    const float* beta_s  = (const float*)d_in[11];
    const float* gamma_e = (const float*)d_in[12];
    const float* beta_e  = (const float*)d_in[13];
    const float* w_gate  = (const float*)d_in[14];
    const float* b_gate  = (const float*)d_in[15];
    float* out = (float*)d_out;

    __hip_bfloat16* qkv  = (__hip_bfloat16*)d_ws;                 // 48 MiB
    __hip_bfloat16* attn = qkv + (size_t)65536 * 384;             // 16 MiB

    // ---- phase 1: row-wise (starting node) attention ----
    proj_qkv_mfma<<<512, 512, 0, stream>>>(pair, w_in_s, b_in_s, qkv, 0);
    attn_mfma_kernel<<<dim3(4, 256), 256, 0, stream>>>(qkv, attn);
    proj_ln_mfma<<<512, 512, 0, stream>>>(attn, w_out_s, b_out_s, pair,
                                          gamma_s, beta_s, out, 0);
    // ---- phase 2: column-wise (ending node) attention, transposed layout ----
    proj_qkv_mfma<<<512, 512, 0, stream>>>(out, w_in_e, b_in_e, qkv, 1);
    attn_mfma_kernel<<<dim3(4, 256), 256, 0, stream>>>(qkv, attn);
    proj_ln_mfma<<<512, 512, 0, stream>>>(attn, w_out_e, b_out_e, out,
                                          gamma_e, beta_e, out, 1);
    // ---- gate ----
    gate_mfma<<<512, 512, 0, stream>>>(out, w_gate, b_gate, out);
}

// Round 4
// 168.445 us; speedup vs baseline: 4.8101x; 1.1034x over previous
//
#include <hip/hip_runtime.h>
#include <hip/hip_bf16.h>
#include <cstddef>

// Problem constants: B=1, L=256, D=128, H=4, hd=32
#define DD 128

typedef unsigned short u16;
typedef short short8v __attribute__((ext_vector_type(8)));   // 8 bf16 (4 VGPRs)
typedef float floatx4 __attribute__((ext_vector_type(4)));   // 4 fp32 acc

__device__ __forceinline__ float bf2f(u16 u) {
    return __uint_as_float(((unsigned int)u) << 16);
}
__device__ __forceinline__ u16 f2b(float x) {   // round-to-nearest-even f32->bf16
    unsigned u = __float_as_uint(x);
    return (u16)((u + 0x7FFF + ((u >> 16) & 1)) >> 16);
}

// Stage a 128x128 fp32 weight block into LDS as bf16, pitch 136 u16 (272 B).
__device__ __forceinline__ void stage_w_bf16(const float* __restrict__ Wf,
                                             u16* __restrict__ Wl, int tid) {
    #pragma unroll
    for (int it = 0; it < 8; ++it) {
        int f = tid + it * 512;           // 4096 float4 chunks
        int row = f >> 5, c4 = f & 31;
        float4 v = reinterpret_cast<const float4*>(Wf + (size_t)row * DD)[c4];
        ushort4 o;
        o.x = f2b(v.x); o.y = f2b(v.y); o.z = f2b(v.z); o.w = f2b(v.w);
        *reinterpret_cast<ushort4*>(&Wl[row * 136 + c4 * 4]) = o;
    }
}

// ---------------- K1: QKV projection, MFMA (unchanged) ----------------
__global__ __launch_bounds__(512) void proj_qkv_mfma(
    const float* __restrict__ X, const float* __restrict__ Wf,
    const float* __restrict__ bias, __hip_bfloat16* __restrict__ Y,
    int transposed)
{
    __shared__ u16 Wl[128 * 136];   // 34816 B
    const int tid = threadIdx.x;
    const int tok0 = blockIdx.x * 128;
    const int lane = tid & 63, wq = tid >> 6;
    const int lq = lane & 15, g = lane >> 4;
    const int t = tok0 + wq * 16 + lq;
    const int xrow = transposed ? ((t & 255) * 256 + (t >> 8)) : t;

    short8v bfrag[4];
    #pragma unroll
    for (int ks = 0; ks < 4; ++ks) {
        const float* p = X + (size_t)xrow * DD + ks * 32 + g * 8;
        float4 a = *reinterpret_cast<const float4*>(p);
        float4 b = *reinterpret_cast<const float4*>(p + 4);
        u16 tmp[8] = { f2b(a.x), f2b(a.y), f2b(a.z), f2b(a.w),
                       f2b(b.x), f2b(b.y), f2b(b.z), f2b(b.w) };
        bfrag[ks] = *reinterpret_cast<const short8v*>(tmp);
    }

    u16* Yt = reinterpret_cast<u16*>(Y) + (size_t)t * 384;

    for (int c = 0; c < 3; ++c) {
        if (c) __syncthreads();
        stage_w_bf16(Wf + (size_t)c * 128 * DD, Wl, tid);
        __syncthreads();
        #pragma unroll
        for (int et = 0; et < 8; ++et) {
            float4 b4 = *reinterpret_cast<const float4*>(bias + c * 128 + et * 16 + g * 4);
            floatx4 acc = { b4.x, b4.y, b4.z, b4.w };
            #pragma unroll
            for (int ks = 0; ks < 4; ++ks) {
                short8v afrag = *reinterpret_cast<const short8v*>(
                    &Wl[(et * 16 + lq) * 136 + ks * 32 + g * 8]);
                acc = __builtin_amdgcn_mfma_f32_16x16x32_bf16(afrag, bfrag[ks], acc, 0, 0, 0);
            }
            ushort4 o;
            o.x = f2b(acc[0]); o.y = f2b(acc[1]); o.z = f2b(acc[2]); o.w = f2b(acc[3]);
            *reinterpret_cast<ushort4*>(&Yt[c * 128 + et * 16 + g * 4]) = o;
        }
    }
}

// ---------------- K2: MFMA attention v3 ----------------
// One block per (head, row). 512 threads = 8 waves; wave wq owns q in [wq*32, wq*32+32),
// processed as 2 tiles of 16. No barriers after staging: P is per-wave, K/Vt read-only.
// Per 32-k tile: pack P slice -> ds_write_b64 x2 -> ds_read_b128 pfrag -> 2 MFMA (PV),
// double-buffered by ks parity so packing of tile ks+1 overlaps reads of tile ks.
__global__ __launch_bounds__(512, 4) void attn_mfma_kernel(
    const __hip_bfloat16* __restrict__ QKV, __hip_bfloat16* __restrict__ O)
{
    constexpr int KP = 40;    // K_lds pitch (u16)
    constexpr int VP = 264;   // Vt pitch (u16)
    constexpr int PP = 40;    // P tile pitch (u16)
    __shared__ u16 K_lds[256 * KP];          // 20480 B
    __shared__ u16 Vt_lds[32 * VP];          // 16896 B
    __shared__ u16 P_lds[8 * 2 * 16 * PP];   // 20480 B  (per-wave 2 x [16][40])

    const int tid = threadIdx.x;
    const int h = blockIdx.x, r = blockIdx.y;
    const u16* q16 = reinterpret_cast<const u16*>(QKV);
    const size_t base = (size_t)r * 256 * 384;

    // ---- stage K row-major: 256 x 32 u16 = 1024 16B chunks over 512 threads ----
    #pragma unroll
    for (int it = 0; it < 2; ++it) {
        int f = tid + it * 512;
        int row = f >> 2, c = f & 3;
        uint4 v = *reinterpret_cast<const uint4*>(q16 + base + (size_t)row * 384 + 128 + h * 32 + c * 8);
        *reinterpret_cast<uint4*>(&K_lds[row * KP + c * 8]) = v;
    }
    // ---- stage V transposed (first 256 threads): Vt[d][k] ----
    if (tid < 256) {
        int dq = tid & 7, ko = tid >> 3;
        int k0 = ko * 8;
        ushort4 col[8];
        #pragma unroll
        for (int j = 0; j < 8; ++j)
            col[j] = *reinterpret_cast<const ushort4*>(
                q16 + base + (size_t)(k0 + j) * 384 + 256 + h * 32 + dq * 4);
        #pragma unroll
        for (int dd = 0; dd < 4; ++dd) {
            u16 vals[8];
            #pragma unroll
            for (int j = 0; j < 8; ++j) vals[j] = reinterpret_cast<const u16*>(&col[j])[dd];
            *reinterpret_cast<uint4*>(&Vt_lds[(dq * 4 + dd) * VP + k0]) =
                *reinterpret_cast<const uint4*>(vals);
        }
    }
    __syncthreads();

    const int lane = tid & 63;
    const int wq = tid >> 6;          // 8 waves
    const int lq = lane & 15;
    const int g  = lane >> 4;

    u16* myP = &P_lds[wq * 2 * 16 * PP];
    const float C1 = 0.25505654196988f;   // (1/sqrt(32)) * log2(e)

    #pragma unroll
    for (int mq = 0; mq < 2; ++mq) {
        const int q0 = wq * 32 + mq * 16;
        // Q B-fragment from global: q = lq, d = g*8 + j
        short8v qfrag = *reinterpret_cast<const short8v*>(
            q16 + base + (size_t)(q0 + lq) * 384 + h * 32 + g * 8);

        // scores: S^T[k][q]; s[ni][rr] = S[k = ni*16 + g*4 + rr][q0 + lq]
        floatx4 s[16];
        #pragma unroll
        for (int ni = 0; ni < 16; ++ni) {
            short8v kfrag = *reinterpret_cast<const short8v*>(&K_lds[(ni * 16 + lq) * KP + g * 8]);
            floatx4 z = {0.f, 0.f, 0.f, 0.f};
            s[ni] = __builtin_amdgcn_mfma_f32_16x16x32_bf16(kfrag, qfrag, z, 0, 0, 0);
        }

        // softmax over k (k lives on this lane + its 3 g-partners)
        float m = -1e30f;
        #pragma unroll
        for (int ni = 0; ni < 16; ++ni)
            m = fmaxf(fmaxf(fmaxf(m, s[ni][0]), fmaxf(s[ni][1], s[ni][2])), s[ni][3]);
        m = fmaxf(m, __shfl_xor(m, 16));
        m = fmaxf(m, __shfl_xor(m, 32));
        const float m1 = m * C1;

        float ell = 0.f;
        #pragma unroll
        for (int ni = 0; ni < 16; ++ni) {
            float p0 = __builtin_amdgcn_exp2f(__builtin_fmaf(s[ni][0], C1, -m1));
            float p1 = __builtin_amdgcn_exp2f(__builtin_fmaf(s[ni][1], C1, -m1));
            float p2 = __builtin_amdgcn_exp2f(__builtin_fmaf(s[ni][2], C1, -m1));
            float p3 = __builtin_amdgcn_exp2f(__builtin_fmaf(s[ni][3], C1, -m1));
            ell += (p0 + p1) + (p2 + p3);
            s[ni][0] = p0; s[ni][1] = p1; s[ni][2] = p2; s[ni][3] = p3;
        }
        ell += __shfl_xor(ell, 16);
        ell += __shfl_xor(ell, 32);

        // PV: O^T[d][q] accumulated tile-by-tile (32 k per tile), no barrier
        floatx4 o0 = {0.f, 0.f, 0.f, 0.f}, o1 = {0.f, 0.f, 0.f, 0.f};
        #pragma unroll
        for (int ks = 0; ks < 8; ++ks) {
            u16* pt = myP + (ks & 1) * 16 * PP;
            // pack this lane's 8 P values of the tile: k = ks*32 + (ni&1)*16 + g*4 + rr
            ushort4 wa, wb;
            wa.x = f2b(s[2*ks][0]);   wa.y = f2b(s[2*ks][1]);
            wa.z = f2b(s[2*ks][2]);   wa.w = f2b(s[2*ks][3]);
            wb.x = f2b(s[2*ks+1][0]); wb.y = f2b(s[2*ks+1][1]);
            wb.z = f2b(s[2*ks+1][2]); wb.w = f2b(s[2*ks+1][3]);
            *reinterpret_cast<ushort4*>(&pt[lq * PP + g * 4])      = wa;
            *reinterpret_cast<ushort4*>(&pt[lq * PP + 16 + g * 4]) = wb;
            // read back as B-fragment: q = lq, kk = g*8 + j
            short8v pfrag = *reinterpret_cast<const short8v*>(&pt[lq * PP + g * 8]);
            short8v v0 = *reinterpret_cast<const short8v*>(&Vt_lds[lq * VP + ks * 32 + g * 8]);
            short8v v1 = *reinterpret_cast<const short8v*>(&Vt_lds[(16 + lq) * VP + ks * 32 + g * 8]);
            o0 = __builtin_amdgcn_mfma_f32_16x16x32_bf16(v0, pfrag, o0, 0, 0, 0);
            o1 = __builtin_amdgcn_mfma_f32_16x16x32_bf16(v1, pfrag, o1, 0, 0, 0);
        }

        const float inv = 1.f / ell;
        // D layout: d = md*16 + g*4 + rr, q = q0 + lq -> 4 consecutive d per lane
        __hip_bfloat16* orow = O + ((size_t)r * 256 + q0 + lq) * 128 + h * 32;
        ushort4 w0, w1;
        w0.x = f2b(o0[0] * inv); w0.y = f2b(o0[1] * inv);
        w0.z = f2b(o0[2] * inv); w0.w = f2b(o0[3] * inv);
        w1.x = f2b(o1[0] * inv); w1.y = f2b(o1[1] * inv);
        w1.z = f2b(o1[2] * inv); w1.w = f2b(o1[3] * inv);
        *reinterpret_cast<ushort4*>(reinterpret_cast<u16*>(orow) + g * 4) = w0;
        *reinterpret_cast<ushort4*>(reinterpret_cast<u16*>(orow) + 16 + g * 4) = w1;
    }
}

// ---------------- K3: out-projection + bias + residual + LayerNorm, MFMA (unchanged) --
__global__ __launch_bounds__(512) void proj_ln_mfma(
    const __hip_bfloat16* __restrict__ A, const float* __restrict__ Wf,
    const float* __restrict__ bias, const float* __restrict__ RES,
    const float* __restrict__ gamma, const float* __restrict__ beta,
    float* __restrict__ OUT, int transposed)
{
    __shared__ u16 Wl[128 * 136];
    const int tid = threadIdx.x;
    const int tok0 = blockIdx.x * 128;
    const int lane = tid & 63, wq = tid >> 6;
    const int lq = lane & 15, g = lane >> 4;
    const int t = tok0 + wq * 16 + lq;
    const int arow = transposed ? ((t & 255) * 256 + (t >> 8)) : t;
    const u16* A16 = reinterpret_cast<const u16*>(A);

    stage_w_bf16(Wf, Wl, tid);

    short8v bfrag[4];
    #pragma unroll
    for (int ks = 0; ks < 4; ++ks)
        bfrag[ks] = *reinterpret_cast<const short8v*>(A16 + (size_t)arow * DD + ks * 32 + g * 8);

    __syncthreads();

    floatx4 acc[8];
    #pragma unroll
    for (int et = 0; et < 8; ++et) {
        float4 b4 = *reinterpret_cast<const float4*>(bias + et * 16 + g * 4);
        float4 r4 = *reinterpret_cast<const float4*>(RES + (size_t)t * DD + et * 16 + g * 4);
        acc[et] = { b4.x + r4.x, b4.y + r4.y, b4.z + r4.z, b4.w + r4.w };
        #pragma unroll
        for (int ks = 0; ks < 4; ++ks) {
            short8v afrag = *reinterpret_cast<const short8v*>(
                &Wl[(et * 16 + lq) * 136 + ks * 32 + g * 8]);
            acc[et] = __builtin_amdgcn_mfma_f32_16x16x32_bf16(afrag, bfrag[ks], acc[et], 0, 0, 0);
        }
    }

    float s = 0.f, ss = 0.f;
    #pragma unroll
    for (int et = 0; et < 8; ++et)
        #pragma unroll
        for (int rr = 0; rr < 4; ++rr) { float v = acc[et][rr]; s += v; ss += v * v; }
    s  += __shfl_xor(s, 16);  s  += __shfl_xor(s, 32);
    ss += __shfl_xor(ss, 16); ss += __shfl_xor(ss, 32);
    float mu = s * (1.f / 128.f);
    float var = ss * (1.f / 128.f) - mu * mu;
    float rstd = rsqrtf(var + 1e-5f);

    #pragma unroll
    for (int et = 0; et < 8; ++et) {
        float4 g4 = *reinterpret_cast<const float4*>(gamma + et * 16 + g * 4);
        float4 be4 = *reinterpret_cast<const float4*>(beta + et * 16 + g * 4);
        float4 o4;
        o4.x = (acc[et][0] - mu) * rstd * g4.x + be4.x;
        o4.y = (acc[et][1] - mu) * rstd * g4.y + be4.y;
        o4.z = (acc[et][2] - mu) * rstd * g4.z + be4.z;
        o4.w = (acc[et][3] - mu) * rstd * g4.w + be4.w;
        *reinterpret_cast<float4*>(OUT + (size_t)t * DD + et * 16 + g * 4) = o4;
    }
}

// ---------------- K4: gate, MFMA (unchanged) ----------------
__global__ __launch_bounds__(512) void gate_mfma(
    const float* __restrict__ P, const float* __restrict__ Wf,
    const float* __restrict__ bias, float* __restrict__ OUT)
{
    __shared__ u16 Wl[128 * 136];
    const int tid = threadIdx.x;
    const int tok0 = blockIdx.x * 128;
    const int lane = tid & 63, wq = tid >> 6;
    const int lq = lane & 15, g = lane >> 4;
    const int t = tok0 + wq * 16 + lq;

    stage_w_bf16(Wf, Wl, tid);

    short8v bfrag[4];
    #pragma unroll
    for (int ks = 0; ks < 4; ++ks) {
        const float* p = P + (size_t)t * DD + ks * 32 + g * 8;
        float4 a = *reinterpret_cast<const float4*>(p);
        float4 b = *reinterpret_cast<const float4*>(p + 4);
        u16 tmp[8] = { f2b(a.x), f2b(a.y), f2b(a.z), f2b(a.w),
                       f2b(b.x), f2b(b.y), f2b(b.z), f2b(b.w) };
        bfrag[ks] = *reinterpret_cast<const short8v*>(tmp);
    }

    __syncthreads();

    floatx4 acc[8];
    #pragma unroll
    for (int et = 0; et < 8; ++et) {
        float4 b4 = *reinterpret_cast<const float4*>(bias + et * 16 + g * 4);
        acc[et] = { b4.x, b4.y, b4.z, b4.w };
        #pragma unroll
        for (int ks = 0; ks < 4; ++ks) {
            short8v afrag = *reinterpret_cast<const short8v*>(
                &Wl[(et * 16 + lq) * 136 + ks * 32 + g * 8]);
            acc[et] = __builtin_amdgcn_mfma_f32_16x16x32_bf16(afrag, bfrag[ks], acc[et], 0, 0, 0);
        }
    }

    float4 pv[8];
    #pragma unroll
    for (int et = 0; et < 8; ++et)
        pv[et] = *reinterpret_cast<const float4*>(P + (size_t)t * DD + et * 16 + g * 4);

    #pragma unroll
    for (int et = 0; et < 8; ++et) {
        float4 o4;
        o4.x = pv[et].x / (1.f + __expf(-acc[et][0]));
        o4.y = pv[et].y / (1.f + __expf(-acc[et][1]));
        o4.z = pv[et].z / (1.f + __expf(-acc[et][2]));
        o4.w = pv[et].w / (1.f + __expf(-acc[et][3]));
        *reinterpret_cast<float4*>(OUT + (size_t)t * DD + et * 16 + g * 4) = o4;
    }
}

extern "C" void kernel_launch(void* const* d_in, const int* in_sizes, int n_in,
                              void* d_out, int out_size, void* d_ws, size_t ws_size,
                              hipStream_t stream) {
    const float* pair    = (const float*)d_in[0];
    const float* w_in_s  = (const float*)d_in[2];
    const float* b_in_s  = (const float*)d_in[3];
    const float* w_out_s = (const float*)d_in[4];
    const float* b_out_s = (const float*)d_in[5];
    const float* w_in_e  = (const float*)d_in[6];
    const float* b_in_e  = (const float*)d_in[7];
    const float* w_out_e = (const float*)d_in[8];
    const float* b_out_e = (const float*)d_in[9];
    const float* gamma_s = (const float*)d_in[10];
    const float* beta_s  = (const float*)d_in[11];
    const float* gamma_e = (const float*)d_in[12];
    const float* beta_e  = (const float*)d_in[13];
    const float* w_gate  = (const float*)d_in[14];
    const float* b_gate  = (const float*)d_in[15];
    float* out = (float*)d_out;

    __hip_bfloat16* qkv  = (__hip_bfloat16*)d_ws;                 // 48 MiB
    __hip_bfloat16* attn = qkv + (size_t)65536 * 384;             // 16 MiB

    // ---- phase 1: row-wise (starting node) attention ----
    proj_qkv_mfma<<<512, 512, 0, stream>>>(pair, w_in_s, b_in_s, qkv, 0);
    attn_mfma_kernel<<<dim3(4, 256), 512, 0, stream>>>(qkv, attn);
    proj_ln_mfma<<<512, 512, 0, stream>>>(attn, w_out_s, b_out_s, pair,
                                          gamma_s, beta_s, out, 0);
    // ---- phase 2: column-wise (ending node) attention, transposed layout ----
    proj_qkv_mfma<<<512, 512, 0, stream>>>(out, w_in_e, b_in_e, qkv, 1);
    attn_mfma_kernel<<<dim3(4, 256), 512, 0, stream>>>(qkv, attn);
    proj_ln_mfma<<<512, 512, 0, stream>>>(attn, w_out_e, b_out_e, out,
                                          gamma_e, beta_e, out, 1);
    // ---- gate ----
    gate_mfma<<<512, 512, 0, stream>>>(out, w_gate, b_gate, out);
}

// Round 5
// 151.092 us; speedup vs baseline: 5.3625x; 1.1148x over previous
//
#include <hip/hip_runtime.h>
#include <hip/hip_bf16.h>
#include <cstddef>

// Problem constants: B=1, L=256, D=128, H=4, hd=32
#define DD 128

typedef unsigned short u16;
typedef short short8v __attribute__((ext_vector_type(8)));   // 8 bf16 (4 VGPRs)
typedef float floatx4 __attribute__((ext_vector_type(4)));   // 4 fp32 acc

__device__ __forceinline__ float bf2f(u16 u) {
    return __uint_as_float(((unsigned int)u) << 16);
}
__device__ __forceinline__ u16 f2b(float x) {   // round-to-nearest-even f32->bf16
    unsigned u = __float_as_uint(x);
    return (u16)((u + 0x7FFF + ((u >> 16) & 1)) >> 16);
}

// Stage a 128x128 fp32 weight block into LDS as bf16, pitch 136 u16 (272 B).
__device__ __forceinline__ void stage_w_bf16(const float* __restrict__ Wf,
                                             u16* __restrict__ Wl, int tid) {
    #pragma unroll
    for (int it = 0; it < 8; ++it) {
        int f = tid + it * 512;           // 4096 float4 chunks
        int row = f >> 5, c4 = f & 31;
        float4 v = reinterpret_cast<const float4*>(Wf + (size_t)row * DD)[c4];
        ushort4 o;
        o.x = f2b(v.x); o.y = f2b(v.y); o.z = f2b(v.z); o.w = f2b(v.w);
        *reinterpret_cast<ushort4*>(&Wl[row * 136 + c4 * 4]) = o;
    }
}

// ---------------- K1: QKV projection, MFMA (unchanged) ----------------
__global__ __launch_bounds__(512) void proj_qkv_mfma(
    const float* __restrict__ X, const float* __restrict__ Wf,
    const float* __restrict__ bias, __hip_bfloat16* __restrict__ Y,
    int transposed)
{
    __shared__ u16 Wl[128 * 136];   // 34816 B
    const int tid = threadIdx.x;
    const int tok0 = blockIdx.x * 128;
    const int lane = tid & 63, wq = tid >> 6;
    const int lq = lane & 15, g = lane >> 4;
    const int t = tok0 + wq * 16 + lq;
    const int xrow = transposed ? ((t & 255) * 256 + (t >> 8)) : t;

    short8v bfrag[4];
    #pragma unroll
    for (int ks = 0; ks < 4; ++ks) {
        const float* p = X + (size_t)xrow * DD + ks * 32 + g * 8;
        float4 a = *reinterpret_cast<const float4*>(p);
        float4 b = *reinterpret_cast<const float4*>(p + 4);
        u16 tmp[8] = { f2b(a.x), f2b(a.y), f2b(a.z), f2b(a.w),
                       f2b(b.x), f2b(b.y), f2b(b.z), f2b(b.w) };
        bfrag[ks] = *reinterpret_cast<const short8v*>(tmp);
    }

    u16* Yt = reinterpret_cast<u16*>(Y) + (size_t)t * 384;

    for (int c = 0; c < 3; ++c) {
        if (c) __syncthreads();
        stage_w_bf16(Wf + (size_t)c * 128 * DD, Wl, tid);
        __syncthreads();
        #pragma unroll
        for (int et = 0; et < 8; ++et) {
            float4 b4 = *reinterpret_cast<const float4*>(bias + c * 128 + et * 16 + g * 4);
            floatx4 acc = { b4.x, b4.y, b4.z, b4.w };
            #pragma unroll
            for (int ks = 0; ks < 4; ++ks) {
                short8v afrag = *reinterpret_cast<const short8v*>(
                    &Wl[(et * 16 + lq) * 136 + ks * 32 + g * 8]);
                acc = __builtin_amdgcn_mfma_f32_16x16x32_bf16(afrag, bfrag[ks], acc, 0, 0, 0);
            }
            ushort4 o;
            o.x = f2b(acc[0]); o.y = f2b(acc[1]); o.z = f2b(acc[2]); o.w = f2b(acc[3]);
            *reinterpret_cast<ushort4*>(&Yt[c * 128 + et * 16 + g * 4]) = o;
        }
    }
}

// ---------------- K2: MFMA attention v4 ----------------
// One block per (head, row). 512 threads = 8 waves; wave wq owns q in [wq*32, wq*32+32).
// Single per-wave P tile (LDS ops within a wave complete in order -> no WAR hazard).
// LDS total 47616 B -> 3 blocks/CU; VGPR pinned <=64 -> 24 waves/CU.
__global__ __launch_bounds__(512, 8) void attn_mfma_kernel(
    const __hip_bfloat16* __restrict__ QKV, __hip_bfloat16* __restrict__ O)
{
    constexpr int KP = 40;    // K_lds pitch (u16)
    constexpr int VP = 264;   // Vt pitch (u16)
    constexpr int PP = 40;    // P tile pitch (u16)
    __shared__ u16 K_lds[256 * KP];      // 20480 B
    __shared__ u16 Vt_lds[32 * VP];      // 16896 B
    __shared__ u16 P_lds[8 * 16 * PP];   // 10240 B

    const int tid = threadIdx.x;
    const int h = blockIdx.x, r = blockIdx.y;
    const u16* q16 = reinterpret_cast<const u16*>(QKV);
    const size_t base = (size_t)r * 256 * 384;

    // ---- stage K row-major: 256 x 32 u16 = 1024 16B chunks over 512 threads ----
    #pragma unroll
    for (int it = 0; it < 2; ++it) {
        int f = tid + it * 512;
        int row = f >> 2, c = f & 3;
        uint4 v = *reinterpret_cast<const uint4*>(q16 + base + (size_t)row * 384 + 128 + h * 32 + c * 8);
        *reinterpret_cast<uint4*>(&K_lds[row * KP + c * 8]) = v;
    }
    // ---- stage V transposed (first 256 threads): Vt[d][k] ----
    if (tid < 256) {
        int dq = tid & 7, ko = tid >> 3;
        int k0 = ko * 8;
        ushort4 col[8];
        #pragma unroll
        for (int j = 0; j < 8; ++j)
            col[j] = *reinterpret_cast<const ushort4*>(
                q16 + base + (size_t)(k0 + j) * 384 + 256 + h * 32 + dq * 4);
        #pragma unroll
        for (int dd = 0; dd < 4; ++dd) {
            u16 vals[8];
            #pragma unroll
            for (int j = 0; j < 8; ++j) vals[j] = reinterpret_cast<const u16*>(&col[j])[dd];
            *reinterpret_cast<uint4*>(&Vt_lds[(dq * 4 + dd) * VP + k0]) =
                *reinterpret_cast<const uint4*>(vals);
        }
    }
    __syncthreads();

    const int lane = tid & 63;
    const int wq = tid >> 6;          // 8 waves
    const int lq = lane & 15;
    const int g  = lane >> 4;

    u16* myP = &P_lds[wq * 16 * PP];
    const float C1 = 0.25505654196988f;   // (1/sqrt(32)) * log2(e)

    // prefetch Q fragments for both q-tiles (independent global loads, hoisted)
    short8v qfragA = *reinterpret_cast<const short8v*>(
        q16 + base + (size_t)(wq * 32 + lq) * 384 + h * 32 + g * 8);
    short8v qfragB = *reinterpret_cast<const short8v*>(
        q16 + base + (size_t)(wq * 32 + 16 + lq) * 384 + h * 32 + g * 8);

    #pragma unroll
    for (int mq = 0; mq < 2; ++mq) {
        const int q0 = wq * 32 + mq * 16;
        const short8v qfrag = mq ? qfragB : qfragA;

        // scores: S^T[k][q]; s[ni][rr] = S[k = ni*16 + g*4 + rr][q0 + lq]
        floatx4 s[16];
        __builtin_amdgcn_s_setprio(1);
        #pragma unroll
        for (int ni = 0; ni < 16; ++ni) {
            short8v kfrag = *reinterpret_cast<const short8v*>(&K_lds[(ni * 16 + lq) * KP + g * 8]);
            floatx4 z = {0.f, 0.f, 0.f, 0.f};
            s[ni] = __builtin_amdgcn_mfma_f32_16x16x32_bf16(kfrag, qfrag, z, 0, 0, 0);
        }
        __builtin_amdgcn_s_setprio(0);

        // softmax over k (k lives on this lane + its 3 g-partners)
        float m = -1e30f;
        #pragma unroll
        for (int ni = 0; ni < 16; ++ni)
            m = fmaxf(fmaxf(fmaxf(m, s[ni][0]), fmaxf(s[ni][1], s[ni][2])), s[ni][3]);
        m = fmaxf(m, __shfl_xor(m, 16));
        m = fmaxf(m, __shfl_xor(m, 32));
        const float m1 = m * C1;

        float ell = 0.f;
        #pragma unroll
        for (int ni = 0; ni < 16; ++ni) {
            float p0 = __builtin_amdgcn_exp2f(__builtin_fmaf(s[ni][0], C1, -m1));
            float p1 = __builtin_amdgcn_exp2f(__builtin_fmaf(s[ni][1], C1, -m1));
            float p2 = __builtin_amdgcn_exp2f(__builtin_fmaf(s[ni][2], C1, -m1));
            float p3 = __builtin_amdgcn_exp2f(__builtin_fmaf(s[ni][3], C1, -m1));
            ell += (p0 + p1) + (p2 + p3);
            s[ni][0] = p0; s[ni][1] = p1; s[ni][2] = p2; s[ni][3] = p3;
        }
        ell += __shfl_xor(ell, 16);
        ell += __shfl_xor(ell, 32);

        // PV: O^T[d][q] accumulated tile-by-tile (32 k per tile), no barrier.
        floatx4 o0 = {0.f, 0.f, 0.f, 0.f}, o1 = {0.f, 0.f, 0.f, 0.f};
        __builtin_amdgcn_s_setprio(1);
        #pragma unroll
        for (int ks = 0; ks < 8; ++ks) {
            // pack this lane's 8 P values of the tile: k = ks*32 + (ni&1)*16 + g*4 + rr
            ushort4 wa, wb;
            wa.x = f2b(s[2*ks][0]);   wa.y = f2b(s[2*ks][1]);
            wa.z = f2b(s[2*ks][2]);   wa.w = f2b(s[2*ks][3]);
            wb.x = f2b(s[2*ks+1][0]); wb.y = f2b(s[2*ks+1][1]);
            wb.z = f2b(s[2*ks+1][2]); wb.w = f2b(s[2*ks+1][3]);
            *reinterpret_cast<ushort4*>(&myP[lq * PP + g * 4])      = wa;
            *reinterpret_cast<ushort4*>(&myP[lq * PP + 16 + g * 4]) = wb;
            // read back as B-fragment: q = lq, kk = g*8 + j
            short8v pfrag = *reinterpret_cast<const short8v*>(&myP[lq * PP + g * 8]);
            short8v v0 = *reinterpret_cast<const short8v*>(&Vt_lds[lq * VP + ks * 32 + g * 8]);
            short8v v1 = *reinterpret_cast<const short8v*>(&Vt_lds[(16 + lq) * VP + ks * 32 + g * 8]);
            o0 = __builtin_amdgcn_mfma_f32_16x16x32_bf16(v0, pfrag, o0, 0, 0, 0);
            o1 = __builtin_amdgcn_mfma_f32_16x16x32_bf16(v1, pfrag, o1, 0, 0, 0);
        }
        __builtin_amdgcn_s_setprio(0);

        const float inv = 1.f / ell;
        // D layout: d = md*16 + g*4 + rr, q = q0 + lq -> 4 consecutive d per lane
        __hip_bfloat16* orow = O + ((size_t)r * 256 + q0 + lq) * 128 + h * 32;
        ushort4 w0, w1;
        w0.x = f2b(o0[0] * inv); w0.y = f2b(o0[1] * inv);
        w0.z = f2b(o0[2] * inv); w0.w = f2b(o0[3] * inv);
        w1.x = f2b(o1[0] * inv); w1.y = f2b(o1[1] * inv);
        w1.z = f2b(o1[2] * inv); w1.w = f2b(o1[3] * inv);
        *reinterpret_cast<ushort4*>(reinterpret_cast<u16*>(orow) + g * 4) = w0;
        *reinterpret_cast<ushort4*>(reinterpret_cast<u16*>(orow) + 16 + g * 4) = w1;
    }
}

// ---------------- K3: out-projection + bias + residual + LayerNorm (phase 1) ------
__global__ __launch_bounds__(512) void proj_ln_mfma(
    const __hip_bfloat16* __restrict__ A, const float* __restrict__ Wf,
    const float* __restrict__ bias, const float* __restrict__ RES,
    const float* __restrict__ gamma, const float* __restrict__ beta,
    float* __restrict__ OUT, int transposed)
{
    __shared__ u16 Wl[128 * 136];
    const int tid = threadIdx.x;
    const int tok0 = blockIdx.x * 128;
    const int lane = tid & 63, wq = tid >> 6;
    const int lq = lane & 15, g = lane >> 4;
    const int t = tok0 + wq * 16 + lq;
    const int arow = transposed ? ((t & 255) * 256 + (t >> 8)) : t;
    const u16* A16 = reinterpret_cast<const u16*>(A);

    stage_w_bf16(Wf, Wl, tid);

    short8v bfrag[4];
    #pragma unroll
    for (int ks = 0; ks < 4; ++ks)
        bfrag[ks] = *reinterpret_cast<const short8v*>(A16 + (size_t)arow * DD + ks * 32 + g * 8);

    __syncthreads();

    floatx4 acc[8];
    #pragma unroll
    for (int et = 0; et < 8; ++et) {
        float4 b4 = *reinterpret_cast<const float4*>(bias + et * 16 + g * 4);
        float4 r4 = *reinterpret_cast<const float4*>(RES + (size_t)t * DD + et * 16 + g * 4);
        acc[et] = { b4.x + r4.x, b4.y + r4.y, b4.z + r4.z, b4.w + r4.w };
        #pragma unroll
        for (int ks = 0; ks < 4; ++ks) {
            short8v afrag = *reinterpret_cast<const short8v*>(
                &Wl[(et * 16 + lq) * 136 + ks * 32 + g * 8]);
            acc[et] = __builtin_amdgcn_mfma_f32_16x16x32_bf16(afrag, bfrag[ks], acc[et], 0, 0, 0);
        }
    }

    float s = 0.f, ss = 0.f;
    #pragma unroll
    for (int et = 0; et < 8; ++et)
        #pragma unroll
        for (int rr = 0; rr < 4; ++rr) { float v = acc[et][rr]; s += v; ss += v * v; }
    s  += __shfl_xor(s, 16);  s  += __shfl_xor(s, 32);
    ss += __shfl_xor(ss, 16); ss += __shfl_xor(ss, 32);
    float mu = s * (1.f / 128.f);
    float var = ss * (1.f / 128.f) - mu * mu;
    float rstd = rsqrtf(var + 1e-5f);

    #pragma unroll
    for (int et = 0; et < 8; ++et) {
        float4 g4 = *reinterpret_cast<const float4*>(gamma + et * 16 + g * 4);
        float4 be4 = *reinterpret_cast<const float4*>(beta + et * 16 + g * 4);
        float4 o4;
        o4.x = (acc[et][0] - mu) * rstd * g4.x + be4.x;
        o4.y = (acc[et][1] - mu) * rstd * g4.y + be4.y;
        o4.z = (acc[et][2] - mu) * rstd * g4.z + be4.z;
        o4.w = (acc[et][3] - mu) * rstd * g4.w + be4.w;
        *reinterpret_cast<float4*>(OUT + (size_t)t * DD + et * 16 + g * 4) = o4;
    }
}

// ---------------- K3b: out-proj + LN + gate fused (phase 2 epilogue) ----------
// y = LN(RES + A@W^T + b); OUT = y * sigmoid(y @ Wg^T + bg)
__global__ __launch_bounds__(512) void proj_ln_gate_mfma(
    const __hip_bfloat16* __restrict__ A, const float* __restrict__ Wf,
    const float* __restrict__ bias, const float* __restrict__ RES,
    const float* __restrict__ gamma, const float* __restrict__ beta,
    const float* __restrict__ Wgf, const float* __restrict__ bg,
    float* __restrict__ OUT, int transposed)
{
    __shared__ u16 Wl[128 * 136];   // Wout, later overwritten with Wg
    __shared__ u16 Yl[128 * 136];   // y (bf16), token-major
    const int tid = threadIdx.x;
    const int tok0 = blockIdx.x * 128;
    const int lane = tid & 63, wq = tid >> 6;
    const int lq = lane & 15, g = lane >> 4;
    const int tl = wq * 16 + lq;
    const int t = tok0 + tl;
    const int arow = transposed ? ((t & 255) * 256 + (t >> 8)) : t;
    const u16* A16 = reinterpret_cast<const u16*>(A);

    stage_w_bf16(Wf, Wl, tid);

    short8v bfrag[4];
    #pragma unroll
    for (int ks = 0; ks < 4; ++ks)
        bfrag[ks] = *reinterpret_cast<const short8v*>(A16 + (size_t)arow * DD + ks * 32 + g * 8);

    __syncthreads();

    floatx4 acc[8];
    #pragma unroll
    for (int et = 0; et < 8; ++et) {
        float4 b4 = *reinterpret_cast<const float4*>(bias + et * 16 + g * 4);
        float4 r4 = *reinterpret_cast<const float4*>(RES + (size_t)t * DD + et * 16 + g * 4);
        acc[et] = { b4.x + r4.x, b4.y + r4.y, b4.z + r4.z, b4.w + r4.w };
        #pragma unroll
        for (int ks = 0; ks < 4; ++ks) {
            short8v afrag = *reinterpret_cast<const short8v*>(
                &Wl[(et * 16 + lq) * 136 + ks * 32 + g * 8]);
            acc[et] = __builtin_amdgcn_mfma_f32_16x16x32_bf16(afrag, bfrag[ks], acc[et], 0, 0, 0);
        }
    }

    float s = 0.f, ss = 0.f;
    #pragma unroll
    for (int et = 0; et < 8; ++et)
        #pragma unroll
        for (int rr = 0; rr < 4; ++rr) { float v = acc[et][rr]; s += v; ss += v * v; }
    s  += __shfl_xor(s, 16);  s  += __shfl_xor(s, 32);
    ss += __shfl_xor(ss, 16); ss += __shfl_xor(ss, 32);
    float mu = s * (1.f / 128.f);
    float var = ss * (1.f / 128.f) - mu * mu;
    float rstd = rsqrtf(var + 1e-5f);

    // y in registers; also write bf16 copy to Yl for the gate GEMM
    #pragma unroll
    for (int et = 0; et < 8; ++et) {
        float4 g4 = *reinterpret_cast<const float4*>(gamma + et * 16 + g * 4);
        float4 be4 = *reinterpret_cast<const float4*>(beta + et * 16 + g * 4);
        acc[et][0] = (acc[et][0] - mu) * rstd * g4.x + be4.x;
        acc[et][1] = (acc[et][1] - mu) * rstd * g4.y + be4.y;
        acc[et][2] = (acc[et][2] - mu) * rstd * g4.z + be4.z;
        acc[et][3] = (acc[et][3] - mu) * rstd * g4.w + be4.w;
        ushort4 yb;
        yb.x = f2b(acc[et][0]); yb.y = f2b(acc[et][1]);
        yb.z = f2b(acc[et][2]); yb.w = f2b(acc[et][3]);
        *reinterpret_cast<ushort4*>(&Yl[tl * 136 + et * 16 + g * 4]) = yb;
    }

    __syncthreads();               // Yl complete; Wl reads done
    stage_w_bf16(Wgf, Wl, tid);    // overwrite Wl with gate weights
    __syncthreads();

    short8v yfrag[4];
    #pragma unroll
    for (int ks = 0; ks < 4; ++ks)
        yfrag[ks] = *reinterpret_cast<const short8v*>(&Yl[tl * 136 + ks * 32 + g * 8]);

    #pragma unroll
    for (int et = 0; et < 8; ++et) {
        float4 b4 = *reinterpret_cast<const float4*>(bg + et * 16 + g * 4);
        floatx4 z = { b4.x, b4.y, b4.z, b4.w };
        #pragma unroll
        for (int ks = 0; ks < 4; ++ks) {
            short8v afrag = *reinterpret_cast<const short8v*>(
                &Wl[(et * 16 + lq) * 136 + ks * 32 + g * 8]);
            z = __builtin_amdgcn_mfma_f32_16x16x32_bf16(afrag, yfrag[ks], z, 0, 0, 0);
        }
        float4 o4;
        o4.x = acc[et][0] / (1.f + __expf(-z[0]));
        o4.y = acc[et][1] / (1.f + __expf(-z[1]));
        o4.z = acc[et][2] / (1.f + __expf(-z[2]));
        o4.w = acc[et][3] / (1.f + __expf(-z[3]));
        *reinterpret_cast<float4*>(OUT + (size_t)t * DD + et * 16 + g * 4) = o4;
    }
}

extern "C" void kernel_launch(void* const* d_in, const int* in_sizes, int n_in,
                              void* d_out, int out_size, void* d_ws, size_t ws_size,
                              hipStream_t stream) {
    const float* pair    = (const float*)d_in[0];
    const float* w_in_s  = (const float*)d_in[2];
    const float* b_in_s  = (const float*)d_in[3];
    const float* w_out_s = (const float*)d_in[4];
    const float* b_out_s = (const float*)d_in[5];
    const float* w_in_e  = (const float*)d_in[6];
    const float* b_in_e  = (const float*)d_in[7];
    const float* w_out_e = (const float*)d_in[8];
    const float* b_out_e = (const float*)d_in[9];
    const float* gamma_s = (const float*)d_in[10];
    const float* beta_s  = (const float*)d_in[11];
    const float* gamma_e = (const float*)d_in[12];
    const float* beta_e  = (const float*)d_in[13];
    const float* w_gate  = (const float*)d_in[14];
    const float* b_gate  = (const float*)d_in[15];
    float* out = (float*)d_out;

    __hip_bfloat16* qkv  = (__hip_bfloat16*)d_ws;                 // 48 MiB
    __hip_bfloat16* attn = qkv + (size_t)65536 * 384;             // 16 MiB

    // ---- phase 1: row-wise (starting node) attention ----
    proj_qkv_mfma<<<512, 512, 0, stream>>>(pair, w_in_s, b_in_s, qkv, 0);
    attn_mfma_kernel<<<dim3(4, 256), 512, 0, stream>>>(qkv, attn);
    proj_ln_mfma<<<512, 512, 0, stream>>>(attn, w_out_s, b_out_s, pair,
                                          gamma_s, beta_s, out, 0);
    // ---- phase 2: column-wise (ending node) attention + fused gate ----
    proj_qkv_mfma<<<512, 512, 0, stream>>>(out, w_in_e, b_in_e, qkv, 1);
    attn_mfma_kernel<<<dim3(4, 256), 512, 0, stream>>>(qkv, attn);
    proj_ln_gate_mfma<<<512, 512, 0, stream>>>(attn, w_out_e, b_out_e, out,
                                               gamma_e, beta_e, w_gate, b_gate,
                                               out, 1);
}

// Round 6
// 141.615 us; speedup vs baseline: 5.7214x; 1.0669x over previous
//
#include <hip/hip_runtime.h>
#include <hip/hip_bf16.h>
#include <cstddef>

// Problem constants: B=1, L=256, D=128, H=4, hd=32
#define DD 128

typedef unsigned short u16;
typedef short short8v __attribute__((ext_vector_type(8)));   // 8 bf16 (4 VGPRs)
typedef float floatx4 __attribute__((ext_vector_type(4)));   // 4 fp32 acc

__device__ __forceinline__ float bf2f(u16 u) {
    return __uint_as_float(((unsigned int)u) << 16);
}
__device__ __forceinline__ u16 f2b(float x) {   // round-to-nearest-even f32->bf16
    unsigned u = __float_as_uint(x);
    return (u16)((u + 0x7FFF + ((u >> 16) & 1)) >> 16);
}
__device__ __forceinline__ unsigned cvtpk_bf16(float lo, float hi) {
    unsigned r;
    asm("v_cvt_pk_bf16_f32 %0, %1, %2" : "=v"(r) : "v"(lo), "v"(hi));
    return r;
}

// Stage a 128x128 fp32 weight block into LDS as bf16, pitch 136 u16 (272 B).
__device__ __forceinline__ void stage_w_bf16(const float* __restrict__ Wf,
                                             u16* __restrict__ Wl, int tid) {
    #pragma unroll
    for (int it = 0; it < 8; ++it) {
        int f = tid + it * 512;           // 4096 float4 chunks
        int row = f >> 5, c4 = f & 31;
        float4 v = reinterpret_cast<const float4*>(Wf + (size_t)row * DD)[c4];
        ushort4 o;
        o.x = f2b(v.x); o.y = f2b(v.y); o.z = f2b(v.z); o.w = f2b(v.w);
        *reinterpret_cast<ushort4*>(&Wl[row * 136 + c4 * 4]) = o;
    }
}

// ---------------- K1: QKV projection, MFMA ----------------
// QK out: [65536][256] bf16 (q at [0,128), k at [128,256))
// VT out: [1024 (r*4+h)][32 d][256 k] bf16  (V pre-transposed for attention)
__global__ __launch_bounds__(512) void proj_qkv_mfma(
    const float* __restrict__ X, const float* __restrict__ Wf,
    const float* __restrict__ bias, __hip_bfloat16* __restrict__ QKo,
    __hip_bfloat16* __restrict__ VTo, int transposed)
{
    __shared__ u16 Wl[128 * 136];   // 34816 B
    const int tid = threadIdx.x;
    const int tok0 = blockIdx.x * 128;
    const int lane = tid & 63, wq = tid >> 6;
    const int lq = lane & 15, g = lane >> 4;
    const int t = tok0 + wq * 16 + lq;
    const int xrow = transposed ? ((t & 255) * 256 + (t >> 8)) : t;

    short8v bfrag[4];
    #pragma unroll
    for (int ks = 0; ks < 4; ++ks) {
        const float* p = X + (size_t)xrow * DD + ks * 32 + g * 8;
        float4 a = *reinterpret_cast<const float4*>(p);
        float4 b = *reinterpret_cast<const float4*>(p + 4);
        u16 tmp[8] = { f2b(a.x), f2b(a.y), f2b(a.z), f2b(a.w),
                       f2b(b.x), f2b(b.y), f2b(b.z), f2b(b.w) };
        bfrag[ks] = *reinterpret_cast<const short8v*>(tmp);
    }

    u16* qkt = reinterpret_cast<u16*>(QKo) + (size_t)t * 256;
    u16* vtb = reinterpret_cast<u16*>(VTo);
    const int rr_ = t >> 8, kk_ = t & 255;

    for (int c = 0; c < 3; ++c) {
        if (c) __syncthreads();
        stage_w_bf16(Wf + (size_t)c * 128 * DD, Wl, tid);
        __syncthreads();
        #pragma unroll
        for (int et = 0; et < 8; ++et) {
            float4 b4 = *reinterpret_cast<const float4*>(bias + c * 128 + et * 16 + g * 4);
            floatx4 acc = { b4.x, b4.y, b4.z, b4.w };
            #pragma unroll
            for (int ks = 0; ks < 4; ++ks) {
                short8v afrag = *reinterpret_cast<const short8v*>(
                    &Wl[(et * 16 + lq) * 136 + ks * 32 + g * 8]);
                acc = __builtin_amdgcn_mfma_f32_16x16x32_bf16(afrag, bfrag[ks], acc, 0, 0, 0);
            }
            if (c < 2) {
                ushort4 o;
                o.x = f2b(acc[0]); o.y = f2b(acc[1]); o.z = f2b(acc[2]); o.w = f2b(acc[3]);
                *reinterpret_cast<ushort4*>(&qkt[c * 128 + et * 16 + g * 4]) = o;
            } else {
                int e = et * 16 + g * 4;          // 0..127 within V block
                int hh = e >> 5, dbase = e & 31;  // head, d-offset
                u16* vb = vtb + ((size_t)(rr_ * 4 + hh) * 32 + dbase) * 256 + kk_;
                vb[0]   = f2b(acc[0]);
                vb[256] = f2b(acc[1]);
                vb[512] = f2b(acc[2]);
                vb[768] = f2b(acc[3]);
            }
        }
    }
}

// ---------------- K2: MFMA attention v5 ----------------
// One block per (head, row). 8 waves; wave wq owns q in [wq*32, wq*32+32).
// P stays in registers: exp -> v_cvt_pk_bf16_f32 packed pairs -> 4x ds_bpermute
// per 32-k tile builds the PV B-fragment. No P LDS, single barrier total.
__global__ __launch_bounds__(512, 6) void attn_mfma_kernel(
    const __hip_bfloat16* __restrict__ QK, const __hip_bfloat16* __restrict__ VT,
    __hip_bfloat16* __restrict__ O)
{
    constexpr int KP = 40;    // K_lds pitch (u16)
    constexpr int VP = 264;   // Vt pitch (u16)
    __shared__ u16 K_lds[256 * KP];      // 20480 B
    __shared__ u16 Vt_lds[32 * VP];      // 16896 B

    const int tid = threadIdx.x;
    const int h = blockIdx.x, r = blockIdx.y;
    const u16* qk = reinterpret_cast<const u16*>(QK) + (size_t)r * 256 * 256;
    const u16* vt = reinterpret_cast<const u16*>(VT) + ((size_t)r * 4 + h) * 8192;

    // ---- stage K row-major: 256 x 32 u16 = 1024 16B chunks ----
    #pragma unroll
    for (int it = 0; it < 2; ++it) {
        int f = tid + it * 512;
        int row = f >> 2, c = f & 3;
        uint4 v = *reinterpret_cast<const uint4*>(qk + (size_t)row * 256 + 128 + h * 32 + c * 8);
        *reinterpret_cast<uint4*>(&K_lds[row * KP + c * 8]) = v;
    }
    // ---- stage Vt (already transposed in global): 32 x 256 u16 = 1024 chunks ----
    #pragma unroll
    for (int it = 0; it < 2; ++it) {
        int f = tid + it * 512;
        int row = f >> 5, c = f & 31;
        uint4 v = *reinterpret_cast<const uint4*>(vt + row * 256 + c * 8);
        *reinterpret_cast<uint4*>(&Vt_lds[row * VP + c * 8]) = v;
    }
    __syncthreads();

    const int lane = tid & 63;
    const int wq = tid >> 6;          // 8 waves
    const int lq = lane & 15;
    const int g  = lane >> 4;
    // bpermute source-lane byte indices (derived pair-redistribution map)
    const int bp0 = ((g & 1) * 32 + lq) * 4;
    const int bp1 = bp0 + 64;
    const bool hi_half = lane >= 32;
    const float C1 = 0.25505654196988f;   // (1/sqrt(32)) * log2(e)

    #pragma unroll
    for (int mq = 0; mq < 2; ++mq) {
        const int q0 = wq * 32 + mq * 16;
        short8v qfrag = *reinterpret_cast<const short8v*>(
            qk + (size_t)(q0 + lq) * 256 + h * 32 + g * 8);

        // scores: S^T[k][q]; s[ni][rr] = S[k = ni*16 + g*4 + rr][q0 + lq]
        floatx4 s[16];
        __builtin_amdgcn_s_setprio(1);
        #pragma unroll
        for (int ni = 0; ni < 16; ++ni) {
            short8v kfrag = *reinterpret_cast<const short8v*>(&K_lds[(ni * 16 + lq) * KP + g * 8]);
            floatx4 z = {0.f, 0.f, 0.f, 0.f};
            s[ni] = __builtin_amdgcn_mfma_f32_16x16x32_bf16(kfrag, qfrag, z, 0, 0, 0);
        }
        __builtin_amdgcn_s_setprio(0);

        // softmax over k
        float m = -1e30f;
        #pragma unroll
        for (int ni = 0; ni < 16; ++ni)
            m = fmaxf(fmaxf(fmaxf(m, s[ni][0]), fmaxf(s[ni][1], s[ni][2])), s[ni][3]);
        m = fmaxf(m, __shfl_xor(m, 16));
        m = fmaxf(m, __shfl_xor(m, 32));
        const float m1 = m * C1;

        float ell = 0.f;
        unsigned u[32];                 // packed bf16 P pairs, statically indexed
        #pragma unroll
        for (int ni = 0; ni < 16; ++ni) {
            float p0 = __builtin_amdgcn_exp2f(__builtin_fmaf(s[ni][0], C1, -m1));
            float p1 = __builtin_amdgcn_exp2f(__builtin_fmaf(s[ni][1], C1, -m1));
            float p2 = __builtin_amdgcn_exp2f(__builtin_fmaf(s[ni][2], C1, -m1));
            float p3 = __builtin_amdgcn_exp2f(__builtin_fmaf(s[ni][3], C1, -m1));
            ell += (p0 + p1) + (p2 + p3);
            u[2 * ni]     = cvtpk_bf16(p0, p1);
            u[2 * ni + 1] = cvtpk_bf16(p2, p3);
        }
        ell += __shfl_xor(ell, 16);
        ell += __shfl_xor(ell, 32);

        // PV: O^T[d][q]; pfrag built in-register via bpermute pair redistribution
        floatx4 o0 = {0.f, 0.f, 0.f, 0.f}, o1 = {0.f, 0.f, 0.f, 0.f};
        __builtin_amdgcn_s_setprio(1);
        #pragma unroll
        for (int ks = 0; ks < 8; ++ks) {
            unsigned Y0 = hi_half ? u[4 * ks + 2] : u[4 * ks];
            unsigned Y1 = hi_half ? u[4 * ks + 3] : u[4 * ks + 1];
            int w0 = __builtin_amdgcn_ds_bpermute(bp0, (int)Y0);
            int w1 = __builtin_amdgcn_ds_bpermute(bp0, (int)Y1);
            int w2 = __builtin_amdgcn_ds_bpermute(bp1, (int)Y0);
            int w3 = __builtin_amdgcn_ds_bpermute(bp1, (int)Y1);
            union { int i[4]; short8v v; } pu;
            pu.i[0] = w0; pu.i[1] = w1; pu.i[2] = w2; pu.i[3] = w3;
            short8v v0 = *reinterpret_cast<const short8v*>(&Vt_lds[lq * VP + ks * 32 + g * 8]);
            short8v v1 = *reinterpret_cast<const short8v*>(&Vt_lds[(16 + lq) * VP + ks * 32 + g * 8]);
            o0 = __builtin_amdgcn_mfma_f32_16x16x32_bf16(v0, pu.v, o0, 0, 0, 0);
            o1 = __builtin_amdgcn_mfma_f32_16x16x32_bf16(v1, pu.v, o1, 0, 0, 0);
        }
        __builtin_amdgcn_s_setprio(0);

        const float inv = 1.f / ell;
        // D layout: d = md*16 + g*4 + rr, q = q0 + lq -> 4 consecutive d per lane
        __hip_bfloat16* orow = O + ((size_t)r * 256 + q0 + lq) * 128 + h * 32;
        ushort4 w0s, w1s;
        w0s.x = f2b(o0[0] * inv); w0s.y = f2b(o0[1] * inv);
        w0s.z = f2b(o0[2] * inv); w0s.w = f2b(o0[3] * inv);
        w1s.x = f2b(o1[0] * inv); w1s.y = f2b(o1[1] * inv);
        w1s.z = f2b(o1[2] * inv); w1s.w = f2b(o1[3] * inv);
        *reinterpret_cast<ushort4*>(reinterpret_cast<u16*>(orow) + g * 4) = w0s;
        *reinterpret_cast<ushort4*>(reinterpret_cast<u16*>(orow) + 16 + g * 4) = w1s;
    }
}

// ---------------- K3: out-projection + bias + residual + LayerNorm (phase 1) ------
__global__ __launch_bounds__(512) void proj_ln_mfma(
    const __hip_bfloat16* __restrict__ A, const float* __restrict__ Wf,
    const float* __restrict__ bias, const float* __restrict__ RES,
    const float* __restrict__ gamma, const float* __restrict__ beta,
    float* __restrict__ OUT, int transposed)
{
    __shared__ u16 Wl[128 * 136];
    const int tid = threadIdx.x;
    const int tok0 = blockIdx.x * 128;
    const int lane = tid & 63, wq = tid >> 6;
    const int lq = lane & 15, g = lane >> 4;
    const int t = tok0 + wq * 16 + lq;
    const int arow = transposed ? ((t & 255) * 256 + (t >> 8)) : t;
    const u16* A16 = reinterpret_cast<const u16*>(A);

    stage_w_bf16(Wf, Wl, tid);

    short8v bfrag[4];
    #pragma unroll
    for (int ks = 0; ks < 4; ++ks)
        bfrag[ks] = *reinterpret_cast<const short8v*>(A16 + (size_t)arow * DD + ks * 32 + g * 8);

    __syncthreads();

    floatx4 acc[8];
    #pragma unroll
    for (int et = 0; et < 8; ++et) {
        float4 b4 = *reinterpret_cast<const float4*>(bias + et * 16 + g * 4);
        float4 r4 = *reinterpret_cast<const float4*>(RES + (size_t)t * DD + et * 16 + g * 4);
        acc[et] = { b4.x + r4.x, b4.y + r4.y, b4.z + r4.z, b4.w + r4.w };
        #pragma unroll
        for (int ks = 0; ks < 4; ++ks) {
            short8v afrag = *reinterpret_cast<const short8v*>(
                &Wl[(et * 16 + lq) * 136 + ks * 32 + g * 8]);
            acc[et] = __builtin_amdgcn_mfma_f32_16x16x32_bf16(afrag, bfrag[ks], acc[et], 0, 0, 0);
        }
    }

    float s = 0.f, ss = 0.f;
    #pragma unroll
    for (int et = 0; et < 8; ++et)
        #pragma unroll
        for (int rr = 0; rr < 4; ++rr) { float v = acc[et][rr]; s += v; ss += v * v; }
    s  += __shfl_xor(s, 16);  s  += __shfl_xor(s, 32);
    ss += __shfl_xor(ss, 16); ss += __shfl_xor(ss, 32);
    float mu = s * (1.f / 128.f);
    float var = ss * (1.f / 128.f) - mu * mu;
    float rstd = rsqrtf(var + 1e-5f);

    #pragma unroll
    for (int et = 0; et < 8; ++et) {
        float4 g4 = *reinterpret_cast<const float4*>(gamma + et * 16 + g * 4);
        float4 be4 = *reinterpret_cast<const float4*>(beta + et * 16 + g * 4);
        float4 o4;
        o4.x = (acc[et][0] - mu) * rstd * g4.x + be4.x;
        o4.y = (acc[et][1] - mu) * rstd * g4.y + be4.y;
        o4.z = (acc[et][2] - mu) * rstd * g4.z + be4.z;
        o4.w = (acc[et][3] - mu) * rstd * g4.w + be4.w;
        *reinterpret_cast<float4*>(OUT + (size_t)t * DD + et * 16 + g * 4) = o4;
    }
}

// ---------------- K3b: out-proj + LN + gate fused (phase 2 epilogue) ----------
__global__ __launch_bounds__(512) void proj_ln_gate_mfma(
    const __hip_bfloat16* __restrict__ A, const float* __restrict__ Wf,
    const float* __restrict__ bias, const float* __restrict__ RES,
    const float* __restrict__ gamma, const float* __restrict__ beta,
    const float* __restrict__ Wgf, const float* __restrict__ bg,
    float* __restrict__ OUT, int transposed)
{
    __shared__ u16 Wl[128 * 136];   // Wout, later overwritten with Wg
    __shared__ u16 Yl[128 * 136];   // y (bf16), token-major
    const int tid = threadIdx.x;
    const int tok0 = blockIdx.x * 128;
    const int lane = tid & 63, wq = tid >> 6;
    const int lq = lane & 15, g = lane >> 4;
    const int tl = wq * 16 + lq;
    const int t = tok0 + tl;
    const int arow = transposed ? ((t & 255) * 256 + (t >> 8)) : t;
    const u16* A16 = reinterpret_cast<const u16*>(A);

    stage_w_bf16(Wf, Wl, tid);

    short8v bfrag[4];
    #pragma unroll
    for (int ks = 0; ks < 4; ++ks)
        bfrag[ks] = *reinterpret_cast<const short8v*>(A16 + (size_t)arow * DD + ks * 32 + g * 8);

    __syncthreads();

    floatx4 acc[8];
    #pragma unroll
    for (int et = 0; et < 8; ++et) {
        float4 b4 = *reinterpret_cast<const float4*>(bias + et * 16 + g * 4);
        float4 r4 = *reinterpret_cast<const float4*>(RES + (size_t)t * DD + et * 16 + g * 4);
        acc[et] = { b4.x + r4.x, b4.y + r4.y, b4.z + r4.z, b4.w + r4.w };
        #pragma unroll
        for (int ks = 0; ks < 4; ++ks) {
            short8v afrag = *reinterpret_cast<const short8v*>(
                &Wl[(et * 16 + lq) * 136 + ks * 32 + g * 8]);
            acc[et] = __builtin_amdgcn_mfma_f32_16x16x32_bf16(afrag, bfrag[ks], acc[et], 0, 0, 0);
        }
    }

    float s = 0.f, ss = 0.f;
    #pragma unroll
    for (int et = 0; et < 8; ++et)
        #pragma unroll
        for (int rr = 0; rr < 4; ++rr) { float v = acc[et][rr]; s += v; ss += v * v; }
    s  += __shfl_xor(s, 16);  s  += __shfl_xor(s, 32);
    ss += __shfl_xor(ss, 16); ss += __shfl_xor(ss, 32);
    float mu = s * (1.f / 128.f);
    float var = ss * (1.f / 128.f) - mu * mu;
    float rstd = rsqrtf(var + 1e-5f);

    #pragma unroll
    for (int et = 0; et < 8; ++et) {
        float4 g4 = *reinterpret_cast<const float4*>(gamma + et * 16 + g * 4);
        float4 be4 = *reinterpret_cast<const float4*>(beta + et * 16 + g * 4);
        acc[et][0] = (acc[et][0] - mu) * rstd * g4.x + be4.x;
        acc[et][1] = (acc[et][1] - mu) * rstd * g4.y + be4.y;
        acc[et][2] = (acc[et][2] - mu) * rstd * g4.z + be4.z;
        acc[et][3] = (acc[et][3] - mu) * rstd * g4.w + be4.w;
        ushort4 yb;
        yb.x = f2b(acc[et][0]); yb.y = f2b(acc[et][1]);
        yb.z = f2b(acc[et][2]); yb.w = f2b(acc[et][3]);
        *reinterpret_cast<ushort4*>(&Yl[tl * 136 + et * 16 + g * 4]) = yb;
    }

    __syncthreads();               // Yl complete; Wl reads done
    stage_w_bf16(Wgf, Wl, tid);    // overwrite Wl with gate weights
    __syncthreads();

    short8v yfrag[4];
    #pragma unroll
    for (int ks = 0; ks < 4; ++ks)
        yfrag[ks] = *reinterpret_cast<const short8v*>(&Yl[tl * 136 + ks * 32 + g * 8]);

    #pragma unroll
    for (int et = 0; et < 8; ++et) {
        float4 b4 = *reinterpret_cast<const float4*>(bg + et * 16 + g * 4);
        floatx4 z = { b4.x, b4.y, b4.z, b4.w };
        #pragma unroll
        for (int ks = 0; ks < 4; ++ks) {
            short8v afrag = *reinterpret_cast<const short8v*>(
                &Wl[(et * 16 + lq) * 136 + ks * 32 + g * 8]);
            z = __builtin_amdgcn_mfma_f32_16x16x32_bf16(afrag, yfrag[ks], z, 0, 0, 0);
        }
        float4 o4;
        o4.x = acc[et][0] / (1.f + __expf(-z[0]));
        o4.y = acc[et][1] / (1.f + __expf(-z[1]));
        o4.z = acc[et][2] / (1.f + __expf(-z[2]));
        o4.w = acc[et][3] / (1.f + __expf(-z[3]));
        *reinterpret_cast<float4*>(OUT + (size_t)t * DD + et * 16 + g * 4) = o4;
    }
}

extern "C" void kernel_launch(void* const* d_in, const int* in_sizes, int n_in,
                              void* d_out, int out_size, void* d_ws, size_t ws_size,
                              hipStream_t stream) {
    const float* pair    = (const float*)d_in[0];
    const float* w_in_s  = (const float*)d_in[2];
    const float* b_in_s  = (const float*)d_in[3];
    const float* w_out_s = (const float*)d_in[4];
    const float* b_out_s = (const float*)d_in[5];
    const float* w_in_e  = (const float*)d_in[6];
    const float* b_in_e  = (const float*)d_in[7];
    const float* w_out_e = (const float*)d_in[8];
    const float* b_out_e = (const float*)d_in[9];
    const float* gamma_s = (const float*)d_in[10];
    const float* beta_s  = (const float*)d_in[11];
    const float* gamma_e = (const float*)d_in[12];
    const float* beta_e  = (const float*)d_in[13];
    const float* w_gate  = (const float*)d_in[14];
    const float* b_gate  = (const float*)d_in[15];
    float* out = (float*)d_out;

    // workspace: QK [65536][256] bf16 (32 MiB) + Vt [1024][32][256] bf16 (16 MiB)
    //          + attn out [65536][128] bf16 (16 MiB)  = 64 MiB
    __hip_bfloat16* qk   = (__hip_bfloat16*)d_ws;
    __hip_bfloat16* vt   = qk + (size_t)65536 * 256;
    __hip_bfloat16* attn = vt + (size_t)1024 * 32 * 256;

    // ---- phase 1: row-wise (starting node) attention ----
    proj_qkv_mfma<<<512, 512, 0, stream>>>(pair, w_in_s, b_in_s, qk, vt, 0);
    attn_mfma_kernel<<<dim3(4, 256), 512, 0, stream>>>(qk, vt, attn);
    proj_ln_mfma<<<512, 512, 0, stream>>>(attn, w_out_s, b_out_s, pair,
                                          gamma_s, beta_s, out, 0);
    // ---- phase 2: column-wise (ending node) attention + fused gate ----
    proj_qkv_mfma<<<512, 512, 0, stream>>>(out, w_in_e, b_in_e, qk, vt, 1);
    attn_mfma_kernel<<<dim3(4, 256), 512, 0, stream>>>(qk, vt, attn);
    proj_ln_gate_mfma<<<512, 512, 0, stream>>>(attn, w_out_e, b_out_e, out,
                                               gamma_e, beta_e, w_gate, b_gate,
                                               out, 1);
}